// Round 1
// baseline (1296.483 us; speedup 1.0000x reference)
//
#include <hip/hip_runtime.h>

#define N_NODES 50000
#define N_EDGES 800000
#define DIM 100

// ---------------- GEMM: hidden = x @ W^T + b ----------------
// One block = 8 rows of x. W staged transposed in LDS (padded +4 so float4
// reads stay aligned and read-side bank conflicts vanish: consecutive c ->
// consecutive banks).
__global__ __launch_bounds__(256) void srgnn_gemm_bias(
    const float* __restrict__ x, const float* __restrict__ W,
    const float* __restrict__ b, float* __restrict__ hidden)
{
    __shared__ float Wt[DIM][DIM + 4];   // Wt[k][c] = W[c][k]
    __shared__ float bs[DIM];
    __shared__ float xs[8][DIM];

    const int t = threadIdx.x;

    for (int i = t; i < DIM * DIM; i += 256) {
        int c = i / DIM, k = i - c * DIM;
        Wt[k][c] = W[i];
    }
    if (t < DIM) bs[t] = b[t];

    const int row0 = blockIdx.x * 8;
    for (int i = t; i < 8 * DIM; i += 256) {
        int r = i / DIM, k = i - r * DIM;
        int row = row0 + r;
        xs[r][k] = (row < N_NODES) ? x[row * DIM + k] : 0.0f;
    }
    __syncthreads();

    // 8 rows x 25 float4-columns = 200 work items, one per thread.
    if (t < 200) {
        const int r  = t / 25;
        const int c4 = (t - r * 25) * 4;
        float acc0 = bs[c4 + 0];
        float acc1 = bs[c4 + 1];
        float acc2 = bs[c4 + 2];
        float acc3 = bs[c4 + 3];
        #pragma unroll 4
        for (int k = 0; k < DIM; ++k) {
            const float xv = xs[r][k];
            const float4 wv = *reinterpret_cast<const float4*>(&Wt[k][c4]);
            acc0 += xv * wv.x;
            acc1 += xv * wv.y;
            acc2 += xv * wv.z;
            acc3 += xv * wv.w;
        }
        const int row = row0 + r;
        if (row < N_NODES) {
            float4 v = make_float4(acc0, acc1, acc2, acc3);
            *reinterpret_cast<float4*>(&hidden[row * DIM + c4]) = v;
        }
    }
}

// ---------------- scatter: out[dst] += hidden[src] * w ----------------
// One thread per (edge, float4-chunk); 25 chunks per edge. Gather of the
// 400B hidden row is coalesced across the 25 consecutive threads; scatter
// is 4 scalar atomicAdds (random dst -> low contention).
__global__ __launch_bounds__(256) void srgnn_scatter(
    const float* __restrict__ hidden, const int* __restrict__ esrc,
    const int* __restrict__ edst, const float* __restrict__ ew,
    float* __restrict__ out)
{
    const unsigned gid = blockIdx.x * 256u + threadIdx.x;
    const unsigned e = gid / 25u;
    const unsigned j = gid - e * 25u;
    if (e >= N_EDGES) return;

    const int   s  = esrc[e];
    const int   d  = edst[e];
    const float wt = ew[e];

    const float4 h = *reinterpret_cast<const float4*>(&hidden[(size_t)s * DIM + j * 4]);

    float* op = &out[(size_t)d * DIM + j * 4];
    atomicAdd(op + 0, h.x * wt);
    atomicAdd(op + 1, h.y * wt);
    atomicAdd(op + 2, h.z * wt);
    atomicAdd(op + 3, h.w * wt);
}

extern "C" void kernel_launch(void* const* d_in, const int* in_sizes, int n_in,
                              void* d_out, int out_size, void* d_ws, size_t ws_size,
                              hipStream_t stream) {
    const float* x    = (const float*)d_in[0];   // [N_NODES, DIM]
    const int*   esrc = (const int*)  d_in[1];   // [N_EDGES]
    const int*   edst = (const int*)  d_in[2];   // [N_EDGES]
    const float* ew   = (const float*)d_in[3];   // [N_EDGES]
    const float* W    = (const float*)d_in[4];   // [DIM, DIM]
    const float* b    = (const float*)d_in[5];   // [DIM]
    float* out = (float*)d_out;                  // [N_NODES, DIM]

    float* hidden = (float*)d_ws;                // 20 MB scratch

    // zero the output (harness poisons it with 0xAA)
    hipMemsetAsync(d_out, 0, (size_t)out_size * sizeof(float), stream);

    // hidden = x @ W^T + b
    const int gemm_blocks = (N_NODES + 7) / 8;
    srgnn_gemm_bias<<<gemm_blocks, 256, 0, stream>>>(x, W, b, hidden);

    // out[dst] += hidden[src] * w
    const long long work = (long long)N_EDGES * 25;
    const int scat_blocks = (int)((work + 255) / 256);
    srgnn_scatter<<<scat_blocks, 256, 0, stream>>>(hidden, esrc, edst, ew, out);
}

// Round 2
// 228.952 us; speedup vs baseline: 5.6627x; 5.6627x over previous
//
#include <hip/hip_runtime.h>

#define N_NODES 50000
#define N_EDGES 800000
#define DIM 100

// ---------------- workspace layout (bytes) ----------------
#define HID_OFF   0u                  // float hidden[50000*100]      20,000,000
#define CNT_OFF   20000000u           // int cnt[50000]                  200,000
#define SCN_OFF   20200000u           // int scn[50000] (local incl)     200,000
#define OFFA_OFF  20400000u           // int off[50001]                  200,004
#define CUR_OFF   20600004u           // int cur[50000]                  200,000
#define PART_OFF  20800004u           // int part[256]                     1,024
#define PARTX_OFF 20801028u           // int partx[256]                    1,024
#define SRCW_OFF  20802056u           // int2 srcw[800000] (8-aligned) 6,400,000
#define WS_NEED   27202056u

#define SCAN_BLOCKS 196               // ceil(50000/256)

// ---------------- GEMM: hidden = x @ W^T + b ----------------
__global__ __launch_bounds__(256) void srgnn_gemm_bias(
    const float* __restrict__ x, const float* __restrict__ W,
    const float* __restrict__ b, float* __restrict__ hidden)
{
    __shared__ float Wt[DIM][DIM + 4];   // Wt[k][c] = W[c][k]
    __shared__ float bs[DIM];
    __shared__ float xs[8][DIM];

    const int t = threadIdx.x;

    for (int i = t; i < DIM * DIM; i += 256) {
        int c = i / DIM, k = i - c * DIM;
        Wt[k][c] = W[i];
    }
    if (t < DIM) bs[t] = b[t];

    const int row0 = blockIdx.x * 8;
    for (int i = t; i < 8 * DIM; i += 256) {
        int r = i / DIM, k = i - r * DIM;
        int row = row0 + r;
        xs[r][k] = (row < N_NODES) ? x[row * DIM + k] : 0.0f;
    }
    __syncthreads();

    if (t < 200) {
        const int r  = t / 25;
        const int c4 = (t - r * 25) * 4;
        float acc0 = bs[c4 + 0];
        float acc1 = bs[c4 + 1];
        float acc2 = bs[c4 + 2];
        float acc3 = bs[c4 + 3];
        #pragma unroll 4
        for (int k = 0; k < DIM; ++k) {
            const float xv = xs[r][k];
            const float4 wv = *reinterpret_cast<const float4*>(&Wt[k][c4]);
            acc0 += xv * wv.x;
            acc1 += xv * wv.y;
            acc2 += xv * wv.z;
            acc3 += xv * wv.w;
        }
        const int row = row0 + r;
        if (row < N_NODES) {
            *reinterpret_cast<float4*>(&hidden[row * DIM + c4]) =
                make_float4(acc0, acc1, acc2, acc3);
        }
    }
}

// ---------------- CSR build ----------------
__global__ __launch_bounds__(256) void srgnn_hist(
    const int* __restrict__ edst, int* __restrict__ cnt)
{
    const unsigned e = blockIdx.x * 256u + threadIdx.x;
    if (e < N_EDGES) atomicAdd(&cnt[edst[e]], 1);
}

// local inclusive scan per 256-block; write incl scan + block total
__global__ __launch_bounds__(256) void srgnn_scan1(
    const int* __restrict__ cnt, int* __restrict__ scn, int* __restrict__ part)
{
    __shared__ int sh[256];
    const int t = threadIdx.x;
    const unsigned i = blockIdx.x * 256u + t;
    int v = (i < N_NODES) ? cnt[i] : 0;
    sh[t] = v;
    __syncthreads();
    #pragma unroll
    for (int ofs = 1; ofs < 256; ofs <<= 1) {
        int a = (t >= ofs) ? sh[t - ofs] : 0;
        __syncthreads();
        sh[t] += a;
        __syncthreads();
    }
    if (i < N_NODES) scn[i] = sh[t];
    if (t == 255) part[blockIdx.x] = sh[255];
}

// scan the 196 block totals -> exclusive prefixes
__global__ __launch_bounds__(256) void srgnn_scan2(
    const int* __restrict__ part, int* __restrict__ partx)
{
    __shared__ int sh[256];
    const int t = threadIdx.x;
    int v = (t < SCAN_BLOCKS) ? part[t] : 0;
    sh[t] = v;
    __syncthreads();
    #pragma unroll
    for (int ofs = 1; ofs < 256; ofs <<= 1) {
        int a = (t >= ofs) ? sh[t - ofs] : 0;
        __syncthreads();
        sh[t] += a;
        __syncthreads();
    }
    partx[t] = sh[t] - v;   // exclusive
}

// off[i] = global exclusive prefix; cur[i] = running cursor copy
__global__ __launch_bounds__(256) void srgnn_scan3(
    const int* __restrict__ cnt, const int* __restrict__ scn,
    const int* __restrict__ partx, int* __restrict__ off, int* __restrict__ cur)
{
    const unsigned i = blockIdx.x * 256u + threadIdx.x;
    if (i < N_NODES) {
        int v = scn[i] - cnt[i] + partx[blockIdx.x];
        off[i] = v;
        cur[i] = v;
    }
    if (i == 0) off[N_NODES] = N_EDGES;
}

// scatter edges into dst-sorted (src, weight) pairs
__global__ __launch_bounds__(256) void srgnn_permute(
    const int* __restrict__ esrc, const int* __restrict__ edst,
    const float* __restrict__ ew, int* __restrict__ cur, int2* __restrict__ srcw)
{
    const unsigned e = blockIdx.x * 256u + threadIdx.x;
    if (e >= N_EDGES) return;
    const int d = edst[e];
    const int pos = atomicAdd(&cur[d], 1);
    srcw[pos] = make_int2(esrc[e], __float_as_int(ew[e]));
}

// ---------------- aggregate: out[n] = sum_e w_e * hidden[src_e] ----------------
// 25-thread group per node; register accumulate; plain float4 store.
__global__ __launch_bounds__(256) void srgnn_aggregate(
    const float* __restrict__ hidden, const int* __restrict__ off,
    const int2* __restrict__ srcw, float* __restrict__ out)
{
    const unsigned gid = blockIdx.x * 256u + threadIdx.x;
    const unsigned n = gid / 25u;
    const unsigned j = gid - n * 25u;
    if (n >= N_NODES) return;

    const int s0 = off[n];
    const int s1 = off[n + 1];
    float4 acc = make_float4(0.f, 0.f, 0.f, 0.f);
    for (int p = s0; p < s1; ++p) {
        const int2 sw = srcw[p];
        const float w = __int_as_float(sw.y);
        const float4 h = *reinterpret_cast<const float4*>(
            &hidden[(size_t)sw.x * DIM + j * 4]);
        acc.x += w * h.x;
        acc.y += w * h.y;
        acc.z += w * h.z;
        acc.w += w * h.w;
    }
    *reinterpret_cast<float4*>(&out[(size_t)n * DIM + j * 4]) = acc;
}

// ---------------- fallback (atomic scatter, needs only 20MB ws) ----------------
__global__ __launch_bounds__(256) void srgnn_scatter_atomic(
    const float* __restrict__ hidden, const int* __restrict__ esrc,
    const int* __restrict__ edst, const float* __restrict__ ew,
    float* __restrict__ out)
{
    const unsigned gid = blockIdx.x * 256u + threadIdx.x;
    const unsigned e = gid / 25u;
    const unsigned j = gid - e * 25u;
    if (e >= N_EDGES) return;
    const int   s  = esrc[e];
    const int   d  = edst[e];
    const float wt = ew[e];
    const float4 h = *reinterpret_cast<const float4*>(&hidden[(size_t)s * DIM + j * 4]);
    float* op = &out[(size_t)d * DIM + j * 4];
    atomicAdd(op + 0, h.x * wt);
    atomicAdd(op + 1, h.y * wt);
    atomicAdd(op + 2, h.z * wt);
    atomicAdd(op + 3, h.w * wt);
}

extern "C" void kernel_launch(void* const* d_in, const int* in_sizes, int n_in,
                              void* d_out, int out_size, void* d_ws, size_t ws_size,
                              hipStream_t stream) {
    const float* x    = (const float*)d_in[0];
    const int*   esrc = (const int*)  d_in[1];
    const int*   edst = (const int*)  d_in[2];
    const float* ew   = (const float*)d_in[3];
    const float* W    = (const float*)d_in[4];
    const float* b    = (const float*)d_in[5];
    float* out = (float*)d_out;

    char* ws = (char*)d_ws;
    float* hidden = (float*)(ws + HID_OFF);

    // GEMM: hidden = x @ W^T + b
    const int gemm_blocks = (N_NODES + 7) / 8;
    srgnn_gemm_bias<<<gemm_blocks, 256, 0, stream>>>(x, W, b, hidden);

    if (ws_size >= WS_NEED) {
        int*  cnt   = (int*) (ws + CNT_OFF);
        int*  scn   = (int*) (ws + SCN_OFF);
        int*  off   = (int*) (ws + OFFA_OFF);
        int*  cur   = (int*) (ws + CUR_OFF);
        int*  part  = (int*) (ws + PART_OFF);
        int*  partx = (int*) (ws + PARTX_OFF);
        int2* srcw  = (int2*)(ws + SRCW_OFF);

        hipMemsetAsync(cnt, 0, N_NODES * sizeof(int), stream);

        const int eblocks = (N_EDGES + 255) / 256;
        srgnn_hist<<<eblocks, 256, 0, stream>>>(edst, cnt);
        srgnn_scan1<<<SCAN_BLOCKS, 256, 0, stream>>>(cnt, scn, part);
        srgnn_scan2<<<1, 256, 0, stream>>>(part, partx);
        srgnn_scan3<<<SCAN_BLOCKS, 256, 0, stream>>>(cnt, scn, partx, off, cur);
        srgnn_permute<<<eblocks, 256, 0, stream>>>(esrc, edst, ew, cur, srcw);

        const long long work = (long long)N_NODES * 25;
        const int agg_blocks = (int)((work + 255) / 256);
        srgnn_aggregate<<<agg_blocks, 256, 0, stream>>>(hidden, off, srcw, out);
    } else {
        // fallback: atomic scatter (R1 path)
        hipMemsetAsync(d_out, 0, (size_t)out_size * sizeof(float), stream);
        const long long work = (long long)N_EDGES * 25;
        const int scat_blocks = (int)((work + 255) / 256);
        srgnn_scatter_atomic<<<scat_blocks, 256, 0, stream>>>(hidden, esrc, edst, ew, out);
    }
}

// Round 3
// 183.925 us; speedup vs baseline: 7.0490x; 1.2448x over previous
//
#include <hip/hip_runtime.h>

#define N_NODES 50000
#define N_EDGES 800000
#define DIM 100

// ---------------- workspace layout (bytes) ----------------
#define HID_OFF   0u                  // float hidden[50000*100]      20,000,000
#define CNT_OFF   20000000u           // int cnt[50000]                  200,000
#define SCN_OFF   20200000u           // int scn[50000] (local incl)     200,000
#define OFFA_OFF  20400000u           // int off[50001]                  200,004
#define CUR_OFF   20600004u           // int cur[50000]                  200,000
#define PART_OFF  20800004u           // int part[256]                     1,024
#define PARTX_OFF 20801028u           // int partx[256]                    1,024
#define SRCW_OFF  20802056u           // int2 srcw[800000] (8-aligned) 6,400,000
#define WS_NEED   27202056u
// Wt[100*100] (40 KB) aliases SRCW region: transpose+gemm run strictly
// before permute writes srcw on the same stream.

#define SCAN_BLOCKS 196               // ceil(50000/256)
#define ROWS_PB 40                    // gemm rows per block (50000/40 = 1250 exact)

// ---------------- transpose: Wt[k][c] = W[c][k] ----------------
__global__ __launch_bounds__(256) void srgnn_transpose(
    const float* __restrict__ W, float* __restrict__ Wt)
{
    const unsigned i = blockIdx.x * 256u + threadIdx.x;
    if (i < DIM * DIM) {
        const int c = i / DIM, k = i - c * DIM;
        Wt[k * DIM + c] = W[i];
    }
}

// ---------------- GEMM: hidden = x @ W^T + b ----------------
// 256 thr/block, 40 rows/block. x rows staged in LDS (conflict-free reads:
// 3 distinct banks/wave, broadcast within 25-lane groups). Wt read as
// coalesced 400B/wave global float4 (L1-resident 40KB). 16 acc/thread ->
// 16 FMA per (1 global f4 + 4 LDS b32): FMA-bound.
__global__ __launch_bounds__(256) void srgnn_gemm2(
    const float* __restrict__ x, const float* __restrict__ Wt,
    const float* __restrict__ b, float* __restrict__ hidden)
{
    __shared__ float xs[ROWS_PB][DIM];   // 16 KB
    const int t = threadIdx.x;
    const int row0 = blockIdx.x * ROWS_PB;

    for (int i = t; i < ROWS_PB * 25; i += 256) {
        const int r = i / 25, c4 = (i - r * 25) * 4;
        const float4 v = *reinterpret_cast<const float4*>(
            &x[(size_t)(row0 + r) * DIM + c4]);
        *reinterpret_cast<float4*>(&xs[r][c4]) = v;
    }
    __syncthreads();

    if (t < 250) {
        const int g  = t / 25;            // row group 0..9
        const int c4 = (t - g * 25) * 4;  // col chunk
        const float4 bv = *reinterpret_cast<const float4*>(&b[c4]);
        float4 a0 = bv, a1 = bv, a2 = bv, a3 = bv;

        #pragma unroll 4
        for (int k = 0; k < DIM; ++k) {
            const float4 wv = *reinterpret_cast<const float4*>(&Wt[k * DIM + c4]);
            const float x0 = xs[g     ][k];
            const float x1 = xs[g + 10][k];
            const float x2 = xs[g + 20][k];
            const float x3 = xs[g + 30][k];
            a0.x += x0 * wv.x; a0.y += x0 * wv.y; a0.z += x0 * wv.z; a0.w += x0 * wv.w;
            a1.x += x1 * wv.x; a1.y += x1 * wv.y; a1.z += x1 * wv.z; a1.w += x1 * wv.w;
            a2.x += x2 * wv.x; a2.y += x2 * wv.y; a2.z += x2 * wv.z; a2.w += x2 * wv.w;
            a3.x += x3 * wv.x; a3.y += x3 * wv.y; a3.z += x3 * wv.z; a3.w += x3 * wv.w;
        }
        *reinterpret_cast<float4*>(&hidden[(size_t)(row0 + g     ) * DIM + c4]) = a0;
        *reinterpret_cast<float4*>(&hidden[(size_t)(row0 + g + 10) * DIM + c4]) = a1;
        *reinterpret_cast<float4*>(&hidden[(size_t)(row0 + g + 20) * DIM + c4]) = a2;
        *reinterpret_cast<float4*>(&hidden[(size_t)(row0 + g + 30) * DIM + c4]) = a3;
    }
}

// ---------------- CSR build ----------------
__global__ __launch_bounds__(256) void srgnn_hist(
    const int* __restrict__ edst, int* __restrict__ cnt)
{
    const unsigned e = blockIdx.x * 256u + threadIdx.x;
    if (e < N_EDGES) atomicAdd(&cnt[edst[e]], 1);
}

__global__ __launch_bounds__(256) void srgnn_scan1(
    const int* __restrict__ cnt, int* __restrict__ scn, int* __restrict__ part)
{
    __shared__ int sh[256];
    const int t = threadIdx.x;
    const unsigned i = blockIdx.x * 256u + t;
    int v = (i < N_NODES) ? cnt[i] : 0;
    sh[t] = v;
    __syncthreads();
    #pragma unroll
    for (int ofs = 1; ofs < 256; ofs <<= 1) {
        int a = (t >= ofs) ? sh[t - ofs] : 0;
        __syncthreads();
        sh[t] += a;
        __syncthreads();
    }
    if (i < N_NODES) scn[i] = sh[t];
    if (t == 255) part[blockIdx.x] = sh[255];
}

__global__ __launch_bounds__(256) void srgnn_scan2(
    const int* __restrict__ part, int* __restrict__ partx)
{
    __shared__ int sh[256];
    const int t = threadIdx.x;
    int v = (t < SCAN_BLOCKS) ? part[t] : 0;
    sh[t] = v;
    __syncthreads();
    #pragma unroll
    for (int ofs = 1; ofs < 256; ofs <<= 1) {
        int a = (t >= ofs) ? sh[t - ofs] : 0;
        __syncthreads();
        sh[t] += a;
        __syncthreads();
    }
    partx[t] = sh[t] - v;   // exclusive
}

__global__ __launch_bounds__(256) void srgnn_scan3(
    const int* __restrict__ cnt, const int* __restrict__ scn,
    const int* __restrict__ partx, int* __restrict__ off, int* __restrict__ cur)
{
    const unsigned i = blockIdx.x * 256u + threadIdx.x;
    if (i < N_NODES) {
        int v = scn[i] - cnt[i] + partx[blockIdx.x];
        off[i] = v;
        cur[i] = v;
    }
    if (i == 0) off[N_NODES] = N_EDGES;
}

__global__ __launch_bounds__(256) void srgnn_permute(
    const int* __restrict__ esrc, const int* __restrict__ edst,
    const float* __restrict__ ew, int* __restrict__ cur, int2* __restrict__ srcw)
{
    const unsigned e = blockIdx.x * 256u + threadIdx.x;
    if (e >= N_EDGES) return;
    const int d = edst[e];
    const int pos = atomicAdd(&cur[d], 1);
    srcw[pos] = make_int2(esrc[e], __float_as_int(ew[e]));
}

// ---------------- aggregate: out[n] = sum_e w_e * hidden[src_e] ----------------
__global__ __launch_bounds__(256) void srgnn_aggregate(
    const float* __restrict__ hidden, const int* __restrict__ off,
    const int2* __restrict__ srcw, float* __restrict__ out)
{
    const unsigned gid = blockIdx.x * 256u + threadIdx.x;
    const unsigned n = gid / 25u;
    const unsigned j = gid - n * 25u;
    if (n >= N_NODES) return;

    const int s0 = off[n];
    const int s1 = off[n + 1];
    float4 acc = make_float4(0.f, 0.f, 0.f, 0.f);
    for (int p = s0; p < s1; ++p) {
        const int2 sw = srcw[p];
        const float w = __int_as_float(sw.y);
        const float4 h = *reinterpret_cast<const float4*>(
            &hidden[(size_t)sw.x * DIM + j * 4]);
        acc.x += w * h.x;
        acc.y += w * h.y;
        acc.z += w * h.z;
        acc.w += w * h.w;
    }
    *reinterpret_cast<float4*>(&out[(size_t)n * DIM + j * 4]) = acc;
}

// ---------------- fallback (atomic scatter) ----------------
__global__ __launch_bounds__(256) void srgnn_gemm_bias(
    const float* __restrict__ x, const float* __restrict__ W,
    const float* __restrict__ b, float* __restrict__ hidden)
{
    __shared__ float Wt[DIM][DIM + 4];
    __shared__ float bs[DIM];
    __shared__ float xs[8][DIM];
    const int t = threadIdx.x;
    for (int i = t; i < DIM * DIM; i += 256) {
        int c = i / DIM, k = i - c * DIM;
        Wt[k][c] = W[i];
    }
    if (t < DIM) bs[t] = b[t];
    const int row0 = blockIdx.x * 8;
    for (int i = t; i < 8 * DIM; i += 256) {
        int r = i / DIM, k = i - r * DIM;
        int row = row0 + r;
        xs[r][k] = (row < N_NODES) ? x[row * DIM + k] : 0.0f;
    }
    __syncthreads();
    if (t < 200) {
        const int r  = t / 25;
        const int c4 = (t - r * 25) * 4;
        float acc0 = bs[c4 + 0], acc1 = bs[c4 + 1], acc2 = bs[c4 + 2], acc3 = bs[c4 + 3];
        for (int k = 0; k < DIM; ++k) {
            const float xv = xs[r][k];
            const float4 wv = *reinterpret_cast<const float4*>(&Wt[k][c4]);
            acc0 += xv * wv.x; acc1 += xv * wv.y; acc2 += xv * wv.z; acc3 += xv * wv.w;
        }
        const int row = row0 + r;
        if (row < N_NODES)
            *reinterpret_cast<float4*>(&hidden[row * DIM + c4]) =
                make_float4(acc0, acc1, acc2, acc3);
    }
}

__global__ __launch_bounds__(256) void srgnn_scatter_atomic(
    const float* __restrict__ hidden, const int* __restrict__ esrc,
    const int* __restrict__ edst, const float* __restrict__ ew,
    float* __restrict__ out)
{
    const unsigned gid = blockIdx.x * 256u + threadIdx.x;
    const unsigned e = gid / 25u;
    const unsigned j = gid - e * 25u;
    if (e >= N_EDGES) return;
    const int   s  = esrc[e];
    const int   d  = edst[e];
    const float wt = ew[e];
    const float4 h = *reinterpret_cast<const float4*>(&hidden[(size_t)s * DIM + j * 4]);
    float* op = &out[(size_t)d * DIM + j * 4];
    atomicAdd(op + 0, h.x * wt);
    atomicAdd(op + 1, h.y * wt);
    atomicAdd(op + 2, h.z * wt);
    atomicAdd(op + 3, h.w * wt);
}

extern "C" void kernel_launch(void* const* d_in, const int* in_sizes, int n_in,
                              void* d_out, int out_size, void* d_ws, size_t ws_size,
                              hipStream_t stream) {
    const float* x    = (const float*)d_in[0];
    const int*   esrc = (const int*)  d_in[1];
    const int*   edst = (const int*)  d_in[2];
    const float* ew   = (const float*)d_in[3];
    const float* W    = (const float*)d_in[4];
    const float* b    = (const float*)d_in[5];
    float* out = (float*)d_out;

    char* ws = (char*)d_ws;
    float* hidden = (float*)(ws + HID_OFF);

    if (ws_size >= WS_NEED) {
        int*   cnt   = (int*)  (ws + CNT_OFF);
        int*   scn   = (int*)  (ws + SCN_OFF);
        int*   off   = (int*)  (ws + OFFA_OFF);
        int*   cur   = (int*)  (ws + CUR_OFF);
        int*   part  = (int*)  (ws + PART_OFF);
        int*   partx = (int*)  (ws + PARTX_OFF);
        int2*  srcw  = (int2*) (ws + SRCW_OFF);
        float* Wt    = (float*)(ws + SRCW_OFF);   // aliases srcw (used before it)

        // GEMM: hidden = x @ W^T + b  (Wt scratch precedes srcw's first write)
        srgnn_transpose<<<(DIM * DIM + 255) / 256, 256, 0, stream>>>(W, Wt);
        srgnn_gemm2<<<N_NODES / ROWS_PB, 256, 0, stream>>>(x, Wt, b, hidden);

        // CSR build
        hipMemsetAsync(cnt, 0, N_NODES * sizeof(int), stream);
        const int eblocks = (N_EDGES + 255) / 256;
        srgnn_hist<<<eblocks, 256, 0, stream>>>(edst, cnt);
        srgnn_scan1<<<SCAN_BLOCKS, 256, 0, stream>>>(cnt, scn, part);
        srgnn_scan2<<<1, 256, 0, stream>>>(part, partx);
        srgnn_scan3<<<SCAN_BLOCKS, 256, 0, stream>>>(cnt, scn, partx, off, cur);
        srgnn_permute<<<eblocks, 256, 0, stream>>>(esrc, edst, ew, cur, srcw);

        // aggregate with plain stores
        const long long work = (long long)N_NODES * 25;
        const int agg_blocks = (int)((work + 255) / 256);
        srgnn_aggregate<<<agg_blocks, 256, 0, stream>>>(hidden, off, srcw, out);
    } else {
        // fallback: atomic scatter
        hipMemsetAsync(d_out, 0, (size_t)out_size * sizeof(float), stream);
        const int gemm_blocks = (N_NODES + 7) / 8;
        srgnn_gemm_bias<<<gemm_blocks, 256, 0, stream>>>(x, W, b, hidden);
        const long long work = (long long)N_EDGES * 25;
        const int scat_blocks = (int)((work + 255) / 256);
        srgnn_scatter_atomic<<<scat_blocks, 256, 0, stream>>>(hidden, esrc, edst, ew, out);
    }
}

// Round 4
// 174.007 us; speedup vs baseline: 7.4508x; 1.0570x over previous
//
#include <hip/hip_runtime.h>

#define N_NODES 50000
#define N_EDGES 800000
#define DIM 100

// ---------------- workspace layout (bytes) ----------------
#define HID_OFF   0u                  // float hidden[50000*100]      20,000,000
#define CNT_OFF   20000000u           // int cnt[50000]                  200,000
#define SCN_OFF   20200000u           // int scn[50000] (local incl)     200,000
#define OFFA_OFF  20400000u           // int off[50001]                  200,004
#define CUR_OFF   20600004u           // int cur[50000]                  200,000
#define PART_OFF  20800004u           // int part[256]                     1,024
#define PARTX_OFF 20801028u           // int partx[256]                    1,024
#define SRCW_OFF  20802056u           // int2 srcw[800000] (8-aligned) 6,400,000
#define WS_NEED   27202056u
// Wt[100*100] (40 KB) aliases SRCW region: transpose+gemm run strictly
// before permute writes srcw on the same stream.

#define SCAN_BLOCKS 196               // ceil(50000/256)
#define ROWS_PB 40                    // gemm rows per block (50000/40 = 1250 exact)

// ---------------- transpose: Wt[k][c] = W[c][k] ----------------
__global__ __launch_bounds__(256) void srgnn_transpose(
    const float* __restrict__ W, float* __restrict__ Wt)
{
    const unsigned i = blockIdx.x * 256u + threadIdx.x;
    if (i < DIM * DIM) {
        const int c = i / DIM, k = i - c * DIM;
        Wt[k * DIM + c] = W[i];
    }
}

// ---------------- GEMM: hidden = x @ W^T + b ----------------
__global__ __launch_bounds__(256) void srgnn_gemm2(
    const float* __restrict__ x, const float* __restrict__ Wt,
    const float* __restrict__ b, float* __restrict__ hidden)
{
    __shared__ float xs[ROWS_PB][DIM];   // 16 KB
    const int t = threadIdx.x;
    const int row0 = blockIdx.x * ROWS_PB;

    for (int i = t; i < ROWS_PB * 25; i += 256) {
        const int r = i / 25, c4 = (i - r * 25) * 4;
        const float4 v = *reinterpret_cast<const float4*>(
            &x[(size_t)(row0 + r) * DIM + c4]);
        *reinterpret_cast<float4*>(&xs[r][c4]) = v;
    }
    __syncthreads();

    if (t < 250) {
        const int g  = t / 25;            // row group 0..9
        const int c4 = (t - g * 25) * 4;  // col chunk
        const float4 bv = *reinterpret_cast<const float4*>(&b[c4]);
        float4 a0 = bv, a1 = bv, a2 = bv, a3 = bv;

        #pragma unroll 4
        for (int k = 0; k < DIM; ++k) {
            const float4 wv = *reinterpret_cast<const float4*>(&Wt[k * DIM + c4]);
            const float x0 = xs[g     ][k];
            const float x1 = xs[g + 10][k];
            const float x2 = xs[g + 20][k];
            const float x3 = xs[g + 30][k];
            a0.x += x0 * wv.x; a0.y += x0 * wv.y; a0.z += x0 * wv.z; a0.w += x0 * wv.w;
            a1.x += x1 * wv.x; a1.y += x1 * wv.y; a1.z += x1 * wv.z; a1.w += x1 * wv.w;
            a2.x += x2 * wv.x; a2.y += x2 * wv.y; a2.z += x2 * wv.z; a2.w += x2 * wv.w;
            a3.x += x3 * wv.x; a3.y += x3 * wv.y; a3.z += x3 * wv.z; a3.w += x3 * wv.w;
        }
        *reinterpret_cast<float4*>(&hidden[(size_t)(row0 + g     ) * DIM + c4]) = a0;
        *reinterpret_cast<float4*>(&hidden[(size_t)(row0 + g + 10) * DIM + c4]) = a1;
        *reinterpret_cast<float4*>(&hidden[(size_t)(row0 + g + 20) * DIM + c4]) = a2;
        *reinterpret_cast<float4*>(&hidden[(size_t)(row0 + g + 30) * DIM + c4]) = a3;
    }
}

// ---------------- CSR build ----------------
__global__ __launch_bounds__(256) void srgnn_hist(
    const int* __restrict__ edst, int* __restrict__ cnt)
{
    const unsigned e = blockIdx.x * 256u + threadIdx.x;
    if (e < N_EDGES) atomicAdd(&cnt[edst[e]], 1);
}

__global__ __launch_bounds__(256) void srgnn_scan1(
    const int* __restrict__ cnt, int* __restrict__ scn, int* __restrict__ part)
{
    __shared__ int sh[256];
    const int t = threadIdx.x;
    const unsigned i = blockIdx.x * 256u + t;
    int v = (i < N_NODES) ? cnt[i] : 0;
    sh[t] = v;
    __syncthreads();
    #pragma unroll
    for (int ofs = 1; ofs < 256; ofs <<= 1) {
        int a = (t >= ofs) ? sh[t - ofs] : 0;
        __syncthreads();
        sh[t] += a;
        __syncthreads();
    }
    if (i < N_NODES) scn[i] = sh[t];
    if (t == 255) part[blockIdx.x] = sh[255];
}

__global__ __launch_bounds__(256) void srgnn_scan2(
    const int* __restrict__ part, int* __restrict__ partx)
{
    __shared__ int sh[256];
    const int t = threadIdx.x;
    int v = (t < SCAN_BLOCKS) ? part[t] : 0;
    sh[t] = v;
    __syncthreads();
    #pragma unroll
    for (int ofs = 1; ofs < 256; ofs <<= 1) {
        int a = (t >= ofs) ? sh[t - ofs] : 0;
        __syncthreads();
        sh[t] += a;
        __syncthreads();
    }
    partx[t] = sh[t] - v;   // exclusive
}

__global__ __launch_bounds__(256) void srgnn_scan3(
    const int* __restrict__ cnt, const int* __restrict__ scn,
    const int* __restrict__ partx, int* __restrict__ off, int* __restrict__ cur)
{
    const unsigned i = blockIdx.x * 256u + threadIdx.x;
    if (i < N_NODES) {
        int v = scn[i] - cnt[i] + partx[blockIdx.x];
        off[i] = v;
        cur[i] = v;
    }
    if (i == 0) off[N_NODES] = N_EDGES;
}

__global__ __launch_bounds__(256) void srgnn_permute(
    const int* __restrict__ esrc, const int* __restrict__ edst,
    const float* __restrict__ ew, int* __restrict__ cur, int2* __restrict__ srcw)
{
    const unsigned e = blockIdx.x * 256u + threadIdx.x;
    if (e >= N_EDGES) return;
    const int d = edst[e];
    const int pos = atomicAdd(&cur[d], 1);
    srcw[pos] = make_int2(esrc[e], __float_as_int(ew[e]));
}

// ---------------- aggregate: out[n] = sum_e w_e * hidden[src_e] ----------------
// One 64-lane wave per node. Edge records for the node loaded in ONE
// coalesced shot (lane p holds edge p, deg<=64 in practice), broadcast via
// __shfl -> gather addresses have no memory dependence -> float2 gathers
// (lanes 0..49 = 100 dims) issue 4-deep for full MLP. Degree imbalance is
// per-wave, absorbed by the scheduler.
__global__ __launch_bounds__(256) void srgnn_aggregate_wave(
    const float* __restrict__ hidden, const int* __restrict__ off,
    const int2* __restrict__ srcw, float* __restrict__ out)
{
    const int lane = threadIdx.x & 63;
    const int n = blockIdx.x * 4 + (threadIdx.x >> 6);
    if (n >= N_NODES) return;

    const int s0  = off[n];
    const int deg = off[n + 1] - s0;

    int2 sw = make_int2(0, 0);
    if (lane < deg) sw = srcw[s0 + lane];   // one coalesced 8B/lane load

    const int dcap = (deg < 64) ? deg : 64;
    float2 acc = make_float2(0.f, 0.f);
    const size_t col = 2u * (unsigned)lane;   // lanes 0..49 cover dims 0..99
    const bool active = (lane < 50);

    int p = 0;
    for (; p + 4 <= dcap; p += 4) {
        const int   s0i = __shfl(sw.x, p + 0);
        const float w0  = __int_as_float(__shfl(sw.y, p + 0));
        const int   s1i = __shfl(sw.x, p + 1);
        const float w1  = __int_as_float(__shfl(sw.y, p + 1));
        const int   s2i = __shfl(sw.x, p + 2);
        const float w2  = __int_as_float(__shfl(sw.y, p + 2));
        const int   s3i = __shfl(sw.x, p + 3);
        const float w3  = __int_as_float(__shfl(sw.y, p + 3));
        if (active) {
            const float2 h0 = *reinterpret_cast<const float2*>(&hidden[(size_t)s0i * DIM + col]);
            const float2 h1 = *reinterpret_cast<const float2*>(&hidden[(size_t)s1i * DIM + col]);
            const float2 h2 = *reinterpret_cast<const float2*>(&hidden[(size_t)s2i * DIM + col]);
            const float2 h3 = *reinterpret_cast<const float2*>(&hidden[(size_t)s3i * DIM + col]);
            acc.x += w0 * h0.x; acc.y += w0 * h0.y;
            acc.x += w1 * h1.x; acc.y += w1 * h1.y;
            acc.x += w2 * h2.x; acc.y += w2 * h2.y;
            acc.x += w3 * h3.x; acc.y += w3 * h3.y;
        }
    }
    for (; p < dcap; ++p) {
        const int   si = __shfl(sw.x, p);
        const float wi = __int_as_float(__shfl(sw.y, p));
        if (active) {
            const float2 h = *reinterpret_cast<const float2*>(&hidden[(size_t)si * DIM + col]);
            acc.x += wi * h.x; acc.y += wi * h.y;
        }
    }
    // ultra-rare deg > 64 tail (P ~ 1e-20 for Binomial(800k, 1/50k), kept for correctness)
    for (p = 64; p < deg; ++p) {
        const int2 swt = srcw[s0 + p];      // uniform address -> broadcast load
        const float wi = __int_as_float(swt.y);
        if (active) {
            const float2 h = *reinterpret_cast<const float2*>(&hidden[(size_t)swt.x * DIM + col]);
            acc.x += wi * h.x; acc.y += wi * h.y;
        }
    }

    if (active)
        *reinterpret_cast<float2*>(&out[(size_t)n * DIM + col]) = acc;
}

// ---------------- fallback (atomic scatter) ----------------
__global__ __launch_bounds__(256) void srgnn_gemm_bias(
    const float* __restrict__ x, const float* __restrict__ W,
    const float* __restrict__ b, float* __restrict__ hidden)
{
    __shared__ float Wt[DIM][DIM + 4];
    __shared__ float bs[DIM];
    __shared__ float xs[8][DIM];
    const int t = threadIdx.x;
    for (int i = t; i < DIM * DIM; i += 256) {
        int c = i / DIM, k = i - c * DIM;
        Wt[k][c] = W[i];
    }
    if (t < DIM) bs[t] = b[t];
    const int row0 = blockIdx.x * 8;
    for (int i = t; i < 8 * DIM; i += 256) {
        int r = i / DIM, k = i - r * DIM;
        int row = row0 + r;
        xs[r][k] = (row < N_NODES) ? x[row * DIM + k] : 0.0f;
    }
    __syncthreads();
    if (t < 200) {
        const int r  = t / 25;
        const int c4 = (t - r * 25) * 4;
        float acc0 = bs[c4 + 0], acc1 = bs[c4 + 1], acc2 = bs[c4 + 2], acc3 = bs[c4 + 3];
        for (int k = 0; k < DIM; ++k) {
            const float xv = xs[r][k];
            const float4 wv = *reinterpret_cast<const float4*>(&Wt[k][c4]);
            acc0 += xv * wv.x; acc1 += xv * wv.y; acc2 += xv * wv.z; acc3 += xv * wv.w;
        }
        const int row = row0 + r;
        if (row < N_NODES)
            *reinterpret_cast<float4*>(&hidden[row * DIM + c4]) =
                make_float4(acc0, acc1, acc2, acc3);
    }
}

__global__ __launch_bounds__(256) void srgnn_scatter_atomic(
    const float* __restrict__ hidden, const int* __restrict__ esrc,
    const int* __restrict__ edst, const float* __restrict__ ew,
    float* __restrict__ out)
{
    const unsigned gid = blockIdx.x * 256u + threadIdx.x;
    const unsigned e = gid / 25u;
    const unsigned j = gid - e * 25u;
    if (e >= N_EDGES) return;
    const int   s  = esrc[e];
    const int   d  = edst[e];
    const float wt = ew[e];
    const float4 h = *reinterpret_cast<const float4*>(&hidden[(size_t)s * DIM + j * 4]);
    float* op = &out[(size_t)d * DIM + j * 4];
    atomicAdd(op + 0, h.x * wt);
    atomicAdd(op + 1, h.y * wt);
    atomicAdd(op + 2, h.z * wt);
    atomicAdd(op + 3, h.w * wt);
}

extern "C" void kernel_launch(void* const* d_in, const int* in_sizes, int n_in,
                              void* d_out, int out_size, void* d_ws, size_t ws_size,
                              hipStream_t stream) {
    const float* x    = (const float*)d_in[0];
    const int*   esrc = (const int*)  d_in[1];
    const int*   edst = (const int*)  d_in[2];
    const float* ew   = (const float*)d_in[3];
    const float* W    = (const float*)d_in[4];
    const float* b    = (const float*)d_in[5];
    float* out = (float*)d_out;

    char* ws = (char*)d_ws;
    float* hidden = (float*)(ws + HID_OFF);

    if (ws_size >= WS_NEED) {
        int*   cnt   = (int*)  (ws + CNT_OFF);
        int*   scn   = (int*)  (ws + SCN_OFF);
        int*   off   = (int*)  (ws + OFFA_OFF);
        int*   cur   = (int*)  (ws + CUR_OFF);
        int*   part  = (int*)  (ws + PART_OFF);
        int*   partx = (int*)  (ws + PARTX_OFF);
        int2*  srcw  = (int2*) (ws + SRCW_OFF);
        float* Wt    = (float*)(ws + SRCW_OFF);   // aliases srcw (used before it)

        // GEMM: hidden = x @ W^T + b
        srgnn_transpose<<<(DIM * DIM + 255) / 256, 256, 0, stream>>>(W, Wt);
        srgnn_gemm2<<<N_NODES / ROWS_PB, 256, 0, stream>>>(x, Wt, b, hidden);

        // CSR build
        hipMemsetAsync(cnt, 0, N_NODES * sizeof(int), stream);
        const int eblocks = (N_EDGES + 255) / 256;
        srgnn_hist<<<eblocks, 256, 0, stream>>>(edst, cnt);
        srgnn_scan1<<<SCAN_BLOCKS, 256, 0, stream>>>(cnt, scn, part);
        srgnn_scan2<<<1, 256, 0, stream>>>(part, partx);
        srgnn_scan3<<<SCAN_BLOCKS, 256, 0, stream>>>(cnt, scn, partx, off, cur);
        srgnn_permute<<<eblocks, 256, 0, stream>>>(esrc, edst, ew, cur, srcw);

        // aggregate: one wave per node, plain stores
        const int agg_blocks = (N_NODES + 3) / 4;   // 4 waves (nodes) per block
        srgnn_aggregate_wave<<<agg_blocks, 256, 0, stream>>>(hidden, off, srcw, out);
    } else {
        // fallback: atomic scatter
        hipMemsetAsync(d_out, 0, (size_t)out_size * sizeof(float), stream);
        const int gemm_blocks = (N_NODES + 7) / 8;
        srgnn_gemm_bias<<<gemm_blocks, 256, 0, stream>>>(x, W, b, hidden);
        const long long work = (long long)N_EDGES * 25;
        const int scat_blocks = (int)((work + 255) / 256);
        srgnn_scatter_atomic<<<scat_blocks, 256, 0, stream>>>(hidden, esrc, edst, ew, out);
    }
}

// Round 5
// 132.240 us; speedup vs baseline: 9.8040x; 1.3158x over previous
//
#include <hip/hip_runtime.h>

#define N_NODES 50000
#define N_EDGES 800000
#define DIM 100

#define CAP     40          // bucket slots per node (max degree ~36 for uniform dst)
#define OVF_CAP 50000       // overflow list capacity (edges)

// ---------------- workspace layout (bytes) ----------------
#define HIDB_OFF  0u            // bf16 hidden, packed uint[50000*50]   10,000,000
#define CNT_OFF   10000000u     // int cnt[50000]                          200,000
#define OVFC_OFF  10200000u     // int ovf_cnt (+pad)                           16
#define OVF_OFF   10200016u     // int4 ovf[50000]                         800,000
#define BKT_OFF   11000016u     // int2 bucket[50000*40]                16,000,000
#define WT_OFF    27000016u     // float Wt[100*100]                        40,000
#define WS_NEED   27040016u

#define ROWS_PB 40              // gemm rows per block (50000/40 = 1250 exact)

// float->bf16 RNE pair pack: lo dim in low ushort
__device__ inline unsigned bf16pair(float lo, float hi) {
    unsigned ulo = __float_as_uint(lo); ulo += 0x7FFFu + ((ulo >> 16) & 1u);
    unsigned uhi = __float_as_uint(hi); uhi += 0x7FFFu + ((uhi >> 16) & 1u);
    return (ulo >> 16) | (uhi & 0xFFFF0000u);
}

// ---------------- transpose: Wt[k][c] = W[c][k] ----------------
__global__ __launch_bounds__(256) void srgnn_transpose(
    const float* __restrict__ W, float* __restrict__ Wt)
{
    const unsigned i = blockIdx.x * 256u + threadIdx.x;
    if (i < DIM * DIM) {
        const int c = i / DIM, k = i - c * DIM;
        Wt[k * DIM + c] = W[i];
    }
}

// ---------------- GEMM: hidden(bf16) = x @ W^T + b ----------------
__global__ __launch_bounds__(256) void srgnn_gemm2b(
    const float* __restrict__ x, const float* __restrict__ Wt,
    const float* __restrict__ b, unsigned* __restrict__ hidU)
{
    __shared__ float xs[ROWS_PB][DIM];   // 16 KB
    const int t = threadIdx.x;
    const int row0 = blockIdx.x * ROWS_PB;

    for (int i = t; i < ROWS_PB * 25; i += 256) {
        const int r = i / 25, c4 = (i - r * 25) * 4;
        const float4 v = *reinterpret_cast<const float4*>(
            &x[(size_t)(row0 + r) * DIM + c4]);
        *reinterpret_cast<float4*>(&xs[r][c4]) = v;
    }
    __syncthreads();

    if (t < 250) {
        const int g  = t / 25;            // row group 0..9
        const int c4 = (t - g * 25) * 4;  // col chunk
        const float4 bv = *reinterpret_cast<const float4*>(&b[c4]);
        float4 a0 = bv, a1 = bv, a2 = bv, a3 = bv;

        #pragma unroll 4
        for (int k = 0; k < DIM; ++k) {
            const float4 wv = *reinterpret_cast<const float4*>(&Wt[k * DIM + c4]);
            const float x0 = xs[g     ][k];
            const float x1 = xs[g + 10][k];
            const float x2 = xs[g + 20][k];
            const float x3 = xs[g + 30][k];
            a0.x += x0 * wv.x; a0.y += x0 * wv.y; a0.z += x0 * wv.z; a0.w += x0 * wv.w;
            a1.x += x1 * wv.x; a1.y += x1 * wv.y; a1.z += x1 * wv.z; a1.w += x1 * wv.w;
            a2.x += x2 * wv.x; a2.y += x2 * wv.y; a2.z += x2 * wv.z; a2.w += x2 * wv.w;
            a3.x += x3 * wv.x; a3.y += x3 * wv.y; a3.z += x3 * wv.z; a3.w += x3 * wv.w;
        }
        const int u0 = c4 >> 1;           // uint index within row (50 uints/row)
        uint2 p;
        p.x = bf16pair(a0.x, a0.y); p.y = bf16pair(a0.z, a0.w);
        *reinterpret_cast<uint2*>(&hidU[(size_t)(row0 + g     ) * 50 + u0]) = p;
        p.x = bf16pair(a1.x, a1.y); p.y = bf16pair(a1.z, a1.w);
        *reinterpret_cast<uint2*>(&hidU[(size_t)(row0 + g + 10) * 50 + u0]) = p;
        p.x = bf16pair(a2.x, a2.y); p.y = bf16pair(a2.z, a2.w);
        *reinterpret_cast<uint2*>(&hidU[(size_t)(row0 + g + 20) * 50 + u0]) = p;
        p.x = bf16pair(a3.x, a3.y); p.y = bf16pair(a3.z, a3.w);
        *reinterpret_cast<uint2*>(&hidU[(size_t)(row0 + g + 30) * 50 + u0]) = p;
    }
}

// ---------------- bucket scatter: one pass, replaces hist+scan+permute ----
__global__ __launch_bounds__(256) void srgnn_bucket(
    const int* __restrict__ esrc, const int* __restrict__ edst,
    const float* __restrict__ ew, int* __restrict__ cnt,
    int* __restrict__ ovfc, int4* __restrict__ ovf, int2* __restrict__ bucket)
{
    const unsigned e = blockIdx.x * 256u + threadIdx.x;
    if (e >= N_EDGES) return;
    const int d = edst[e];
    const int s = esrc[e];
    const int wbits = __float_as_int(ew[e]);
    const int pos = atomicAdd(&cnt[d], 1);
    if (pos < CAP) {
        bucket[(size_t)d * CAP + pos] = make_int2(s, wbits);
    } else {
        const int op = atomicAdd(ovfc, 1);
        if (op < OVF_CAP) ovf[op] = make_int4(d, s, wbits, 0);
    }
}

// ---------------- aggregate: out[n] = sum_e w_e * hidden[src_e] ----------
// One wave per node; bucket records loaded in one coalesced shot (lane p =
// edge p), shfl-broadcast -> bf16 row gathers (4B/lane, lanes 0..49) issue
// 4-deep with no memory dependence. Rare deg>CAP handled by in-wave scan
// of the tiny overflow list.
__global__ __launch_bounds__(256) void srgnn_agg_bf16(
    const unsigned* __restrict__ hidU, const int* __restrict__ cnt,
    const int2* __restrict__ bucket, const int* __restrict__ ovfc,
    const int4* __restrict__ ovf, float* __restrict__ out)
{
    const int lane = threadIdx.x & 63;
    const int n = blockIdx.x * 4 + (threadIdx.x >> 6);
    if (n >= N_NODES) return;

    const int degt = cnt[n];
    const int dcap = (degt < CAP) ? degt : CAP;

    int2 sw = make_int2(0, 0);
    if (lane < dcap) sw = bucket[(size_t)n * CAP + lane];

    const bool active = (lane < 50);
    float2 acc = make_float2(0.f, 0.f);

    int p = 0;
    for (; p + 4 <= dcap; p += 4) {
        const int   s0i = __shfl(sw.x, p + 0);
        const float w0  = __int_as_float(__shfl(sw.y, p + 0));
        const int   s1i = __shfl(sw.x, p + 1);
        const float w1  = __int_as_float(__shfl(sw.y, p + 1));
        const int   s2i = __shfl(sw.x, p + 2);
        const float w2  = __int_as_float(__shfl(sw.y, p + 2));
        const int   s3i = __shfl(sw.x, p + 3);
        const float w3  = __int_as_float(__shfl(sw.y, p + 3));
        if (active) {
            const unsigned h0 = hidU[(size_t)s0i * 50 + lane];
            const unsigned h1 = hidU[(size_t)s1i * 50 + lane];
            const unsigned h2 = hidU[(size_t)s2i * 50 + lane];
            const unsigned h3 = hidU[(size_t)s3i * 50 + lane];
            acc.x += w0 * __uint_as_float(h0 << 16);
            acc.y += w0 * __uint_as_float(h0 & 0xFFFF0000u);
            acc.x += w1 * __uint_as_float(h1 << 16);
            acc.y += w1 * __uint_as_float(h1 & 0xFFFF0000u);
            acc.x += w2 * __uint_as_float(h2 << 16);
            acc.y += w2 * __uint_as_float(h2 & 0xFFFF0000u);
            acc.x += w3 * __uint_as_float(h3 << 16);
            acc.y += w3 * __uint_as_float(h3 & 0xFFFF0000u);
        }
    }
    for (; p < dcap; ++p) {
        const int   si = __shfl(sw.x, p);
        const float wi = __int_as_float(__shfl(sw.y, p));
        if (active) {
            const unsigned h = hidU[(size_t)si * 50 + lane];
            acc.x += wi * __uint_as_float(h << 16);
            acc.y += wi * __uint_as_float(h & 0xFFFF0000u);
        }
    }

    if (degt > CAP) {     // ultra-rare: this node overflowed the bucket
        int oc = *ovfc;
        if (oc > OVF_CAP) oc = OVF_CAP;
        for (int i = 0; i < oc; ++i) {
            const int4 t = ovf[i];
            if (t.x == n && active) {
                const unsigned h = hidU[(size_t)t.y * 50 + lane];
                const float wi = __int_as_float(t.z);
                acc.x += wi * __uint_as_float(h << 16);
                acc.y += wi * __uint_as_float(h & 0xFFFF0000u);
            }
        }
    }

    if (active)
        *reinterpret_cast<float2*>(&out[(size_t)n * DIM + 2 * lane]) = acc;
}

// ---------------- fallback (atomic scatter, needs only 20MB ws) ----------
__global__ __launch_bounds__(256) void srgnn_gemm_bias(
    const float* __restrict__ x, const float* __restrict__ W,
    const float* __restrict__ b, float* __restrict__ hidden)
{
    __shared__ float Wt[DIM][DIM + 4];
    __shared__ float bs[DIM];
    __shared__ float xs[8][DIM];
    const int t = threadIdx.x;
    for (int i = t; i < DIM * DIM; i += 256) {
        int c = i / DIM, k = i - c * DIM;
        Wt[k][c] = W[i];
    }
    if (t < DIM) bs[t] = b[t];
    const int row0 = blockIdx.x * 8;
    for (int i = t; i < 8 * DIM; i += 256) {
        int r = i / DIM, k = i - r * DIM;
        int row = row0 + r;
        xs[r][k] = (row < N_NODES) ? x[row * DIM + k] : 0.0f;
    }
    __syncthreads();
    if (t < 200) {
        const int r  = t / 25;
        const int c4 = (t - r * 25) * 4;
        float acc0 = bs[c4 + 0], acc1 = bs[c4 + 1], acc2 = bs[c4 + 2], acc3 = bs[c4 + 3];
        for (int k = 0; k < DIM; ++k) {
            const float xv = xs[r][k];
            const float4 wv = *reinterpret_cast<const float4*>(&Wt[k][c4]);
            acc0 += xv * wv.x; acc1 += xv * wv.y; acc2 += xv * wv.z; acc3 += xv * wv.w;
        }
        const int row = row0 + r;
        if (row < N_NODES)
            *reinterpret_cast<float4*>(&hidden[row * DIM + c4]) =
                make_float4(acc0, acc1, acc2, acc3);
    }
}

__global__ __launch_bounds__(256) void srgnn_scatter_atomic(
    const float* __restrict__ hidden, const int* __restrict__ esrc,
    const int* __restrict__ edst, const float* __restrict__ ew,
    float* __restrict__ out)
{
    const unsigned gid = blockIdx.x * 256u + threadIdx.x;
    const unsigned e = gid / 25u;
    const unsigned j = gid - e * 25u;
    if (e >= N_EDGES) return;
    const int   s  = esrc[e];
    const int   d  = edst[e];
    const float wt = ew[e];
    const float4 h = *reinterpret_cast<const float4*>(&hidden[(size_t)s * DIM + j * 4]);
    float* op = &out[(size_t)d * DIM + j * 4];
    atomicAdd(op + 0, h.x * wt);
    atomicAdd(op + 1, h.y * wt);
    atomicAdd(op + 2, h.z * wt);
    atomicAdd(op + 3, h.w * wt);
}

extern "C" void kernel_launch(void* const* d_in, const int* in_sizes, int n_in,
                              void* d_out, int out_size, void* d_ws, size_t ws_size,
                              hipStream_t stream) {
    const float* x    = (const float*)d_in[0];
    const int*   esrc = (const int*)  d_in[1];
    const int*   edst = (const int*)  d_in[2];
    const float* ew   = (const float*)d_in[3];
    const float* W    = (const float*)d_in[4];
    const float* b    = (const float*)d_in[5];
    float* out = (float*)d_out;

    char* ws = (char*)d_ws;

    if (ws_size >= WS_NEED) {
        unsigned* hidU = (unsigned*)(ws + HIDB_OFF);
        int*      cnt  = (int*)     (ws + CNT_OFF);
        int*      ovfc = (int*)     (ws + OVFC_OFF);
        int4*     ovf  = (int4*)    (ws + OVF_OFF);
        int2*     bkt  = (int2*)    (ws + BKT_OFF);
        float*    Wt   = (float*)   (ws + WT_OFF);

        // GEMM: hidden(bf16) = x @ W^T + b
        srgnn_transpose<<<(DIM * DIM + 255) / 256, 256, 0, stream>>>(W, Wt);
        srgnn_gemm2b<<<N_NODES / ROWS_PB, 256, 0, stream>>>(x, Wt, b, hidU);

        // zero cnt + ovf counter (contiguous), then single-pass bucket scatter
        hipMemsetAsync(cnt, 0, N_NODES * sizeof(int) + 16, stream);
        const int eblocks = (N_EDGES + 255) / 256;
        srgnn_bucket<<<eblocks, 256, 0, stream>>>(esrc, edst, ew, cnt, ovfc, ovf, bkt);

        // aggregate: one wave per node, plain stores
        const int agg_blocks = (N_NODES + 3) / 4;
        srgnn_agg_bf16<<<agg_blocks, 256, 0, stream>>>(hidU, cnt, bkt, ovfc, ovf, out);
    } else {
        // fallback: atomic scatter
        float* hidden = (float*)ws;
        hipMemsetAsync(d_out, 0, (size_t)out_size * sizeof(float), stream);
        const int gemm_blocks = (N_NODES + 7) / 8;
        srgnn_gemm_bias<<<gemm_blocks, 256, 0, stream>>>(x, W, b, hidden);
        const long long work = (long long)N_EDGES * 25;
        const int scat_blocks = (int)((work + 255) / 256);
        srgnn_scatter_atomic<<<scat_blocks, 256, 0, stream>>>(hidden, esrc, edst, ew, out);
    }
}

// Round 6
// 131.596 us; speedup vs baseline: 9.8520x; 1.0049x over previous
//
#include <hip/hip_runtime.h>

#define N_NODES 50000
#define N_EDGES 800000
#define DIM 100

#define CAP     32          // records per node bucket row = 128 B = 2 lines
#define OVF_CAP 50000       // overflow list capacity (edges)

// ---------------- workspace layout (bytes) ----------------
#define HIDB_OFF  0u            // bf16 hidden, packed uint[50000*50]   10,000,000
#define CNT_OFF   10000000u     // int cnt[50000]                          200,000
#define OVFC_OFF  10200000u     // int ovf_cnt (+pad)                           16
#define OVF_OFF   10200016u     // int4 ovf[50000]                         800,000
#define BKT_OFF   11000064u     // uint bucket[50000*32] (128B-aligned)  6,400,000
#define WT_OFF    17400064u     // float Wt[100*100]                        40,000
#define WS_NEED   17440064u

#define ROWS_PB 40              // gemm rows per block (50000/40 = 1250 exact)

// float->bf16 RNE, low 16 bits of result
__device__ inline unsigned bf16r(float v) {
    unsigned u = __float_as_uint(v);
    u += 0x7FFFu + ((u >> 16) & 1u);
    return u >> 16;
}
// float->bf16 RNE pair pack: lo dim in low ushort
__device__ inline unsigned bf16pair(float lo, float hi) {
    unsigned ulo = __float_as_uint(lo); ulo += 0x7FFFu + ((ulo >> 16) & 1u);
    unsigned uhi = __float_as_uint(hi); uhi += 0x7FFFu + ((uhi >> 16) & 1u);
    return (ulo >> 16) | (uhi & 0xFFFF0000u);
}

// ---------------- transpose: Wt[k][c] = W[c][k] ----------------
__global__ __launch_bounds__(256) void srgnn_transpose(
    const float* __restrict__ W, float* __restrict__ Wt)
{
    const unsigned i = blockIdx.x * 256u + threadIdx.x;
    if (i < DIM * DIM) {
        const int c = i / DIM, k = i - c * DIM;
        Wt[k * DIM + c] = W[i];
    }
}

// ---------------- GEMM: hidden(bf16) = x @ W^T + b ----------------
__global__ __launch_bounds__(256) void srgnn_gemm2b(
    const float* __restrict__ x, const float* __restrict__ Wt,
    const float* __restrict__ b, unsigned* __restrict__ hidU)
{
    __shared__ float xs[ROWS_PB][DIM];   // 16 KB
    const int t = threadIdx.x;
    const int row0 = blockIdx.x * ROWS_PB;

    for (int i = t; i < ROWS_PB * 25; i += 256) {
        const int r = i / 25, c4 = (i - r * 25) * 4;
        const float4 v = *reinterpret_cast<const float4*>(
            &x[(size_t)(row0 + r) * DIM + c4]);
        *reinterpret_cast<float4*>(&xs[r][c4]) = v;
    }
    __syncthreads();

    if (t < 250) {
        const int g  = t / 25;            // row group 0..9
        const int c4 = (t - g * 25) * 4;  // col chunk
        const float4 bv = *reinterpret_cast<const float4*>(&b[c4]);
        float4 a0 = bv, a1 = bv, a2 = bv, a3 = bv;

        #pragma unroll 4
        for (int k = 0; k < DIM; ++k) {
            const float4 wv = *reinterpret_cast<const float4*>(&Wt[k * DIM + c4]);
            const float x0 = xs[g     ][k];
            const float x1 = xs[g + 10][k];
            const float x2 = xs[g + 20][k];
            const float x3 = xs[g + 30][k];
            a0.x += x0 * wv.x; a0.y += x0 * wv.y; a0.z += x0 * wv.z; a0.w += x0 * wv.w;
            a1.x += x1 * wv.x; a1.y += x1 * wv.y; a1.z += x1 * wv.z; a1.w += x1 * wv.w;
            a2.x += x2 * wv.x; a2.y += x2 * wv.y; a2.z += x2 * wv.z; a2.w += x2 * wv.w;
            a3.x += x3 * wv.x; a3.y += x3 * wv.y; a3.z += x3 * wv.z; a3.w += x3 * wv.w;
        }
        const int u0 = c4 >> 1;           // uint index within row (50 uints/row)
        uint2 p;
        p.x = bf16pair(a0.x, a0.y); p.y = bf16pair(a0.z, a0.w);
        *reinterpret_cast<uint2*>(&hidU[(size_t)(row0 + g     ) * 50 + u0]) = p;
        p.x = bf16pair(a1.x, a1.y); p.y = bf16pair(a1.z, a1.w);
        *reinterpret_cast<uint2*>(&hidU[(size_t)(row0 + g + 10) * 50 + u0]) = p;
        p.x = bf16pair(a2.x, a2.y); p.y = bf16pair(a2.z, a2.w);
        *reinterpret_cast<uint2*>(&hidU[(size_t)(row0 + g + 20) * 50 + u0]) = p;
        p.x = bf16pair(a3.x, a3.y); p.y = bf16pair(a3.z, a3.w);
        *reinterpret_cast<uint2*>(&hidU[(size_t)(row0 + g + 30) * 50 + u0]) = p;
    }
}

// ---------------- bucket scatter: 4B records, 128B (2-line) rows ----------
__global__ __launch_bounds__(256) void srgnn_bucket4(
    const int* __restrict__ esrc, const int* __restrict__ edst,
    const float* __restrict__ ew, int* __restrict__ cnt,
    int* __restrict__ ovfc, int4* __restrict__ ovf, unsigned* __restrict__ bucket)
{
    const unsigned e = blockIdx.x * 256u + threadIdx.x;
    if (e >= N_EDGES) return;
    const int d = edst[e];
    const int s = esrc[e];
    const float w = ew[e];
    const int pos = atomicAdd(&cnt[d], 1);
    if (pos < CAP) {
        bucket[(size_t)d * CAP + pos] = (unsigned)s | (bf16r(w) << 16);
    } else {
        const int op = atomicAdd(ovfc, 1);
        if (op < OVF_CAP) ovf[op] = make_int4(d, s, __float_as_int(w), 0);
    }
}

// ---------------- aggregate: out[n] = sum_e w_e * hidden[src_e] ----------
// One wave per node; 32 packed records loaded in one 128B coalesced shot,
// shfl-broadcast -> bf16 row gathers (4B/lane, lanes 0..49) issue 4-deep
// with no memory dependence. w unpacks from the record's high half.
__global__ __launch_bounds__(256) void srgnn_agg_p4(
    const unsigned* __restrict__ hidU, const int* __restrict__ cnt,
    const unsigned* __restrict__ bucket, const int* __restrict__ ovfc,
    const int4* __restrict__ ovf, float* __restrict__ out)
{
    const int lane = threadIdx.x & 63;
    const int n = blockIdx.x * 4 + (threadIdx.x >> 6);
    if (n >= N_NODES) return;

    const int degt = cnt[n];
    const int dcap = (degt < CAP) ? degt : CAP;

    unsigned rec = 0;
    if (lane < dcap) rec = bucket[(size_t)n * CAP + lane];

    const bool active = (lane < 50);
    float2 acc = make_float2(0.f, 0.f);

    int p = 0;
    for (; p + 4 <= dcap; p += 4) {
        const unsigned r0 = __shfl(rec, p + 0);
        const unsigned r1 = __shfl(rec, p + 1);
        const unsigned r2 = __shfl(rec, p + 2);
        const unsigned r3 = __shfl(rec, p + 3);
        const float w0 = __uint_as_float(r0 & 0xFFFF0000u);
        const float w1 = __uint_as_float(r1 & 0xFFFF0000u);
        const float w2 = __uint_as_float(r2 & 0xFFFF0000u);
        const float w3 = __uint_as_float(r3 & 0xFFFF0000u);
        if (active) {
            const unsigned h0 = hidU[(size_t)(r0 & 0xFFFFu) * 50 + lane];
            const unsigned h1 = hidU[(size_t)(r1 & 0xFFFFu) * 50 + lane];
            const unsigned h2 = hidU[(size_t)(r2 & 0xFFFFu) * 50 + lane];
            const unsigned h3 = hidU[(size_t)(r3 & 0xFFFFu) * 50 + lane];
            acc.x += w0 * __uint_as_float(h0 << 16);
            acc.y += w0 * __uint_as_float(h0 & 0xFFFF0000u);
            acc.x += w1 * __uint_as_float(h1 << 16);
            acc.y += w1 * __uint_as_float(h1 & 0xFFFF0000u);
            acc.x += w2 * __uint_as_float(h2 << 16);
            acc.y += w2 * __uint_as_float(h2 & 0xFFFF0000u);
            acc.x += w3 * __uint_as_float(h3 << 16);
            acc.y += w3 * __uint_as_float(h3 & 0xFFFF0000u);
        }
    }
    for (; p < dcap; ++p) {
        const unsigned r = __shfl(rec, p);
        const float wi = __uint_as_float(r & 0xFFFF0000u);
        if (active) {
            const unsigned h = hidU[(size_t)(r & 0xFFFFu) * 50 + lane];
            acc.x += wi * __uint_as_float(h << 16);
            acc.y += wi * __uint_as_float(h & 0xFFFF0000u);
        }
    }

    if (degt > CAP) {     // ultra-rare: scan tiny overflow list
        int oc = *ovfc;
        if (oc > OVF_CAP) oc = OVF_CAP;
        for (int i = 0; i < oc; ++i) {
            const int4 t = ovf[i];
            if (t.x == n && active) {
                const unsigned h = hidU[(size_t)t.y * 50 + lane];
                const float wi = __int_as_float(t.z);
                acc.x += wi * __uint_as_float(h << 16);
                acc.y += wi * __uint_as_float(h & 0xFFFF0000u);
            }
        }
    }

    if (active)
        *reinterpret_cast<float2*>(&out[(size_t)n * DIM + 2 * lane]) = acc;
}

// ---------------- fallback (atomic scatter, needs only 20MB ws) ----------
__global__ __launch_bounds__(256) void srgnn_gemm_bias(
    const float* __restrict__ x, const float* __restrict__ W,
    const float* __restrict__ b, float* __restrict__ hidden)
{
    __shared__ float Wt[DIM][DIM + 4];
    __shared__ float bs[DIM];
    __shared__ float xs[8][DIM];
    const int t = threadIdx.x;
    for (int i = t; i < DIM * DIM; i += 256) {
        int c = i / DIM, k = i - c * DIM;
        Wt[k][c] = W[i];
    }
    if (t < DIM) bs[t] = b[t];
    const int row0 = blockIdx.x * 8;
    for (int i = t; i < 8 * DIM; i += 256) {
        int r = i / DIM, k = i - r * DIM;
        int row = row0 + r;
        xs[r][k] = (row < N_NODES) ? x[row * DIM + k] : 0.0f;
    }
    __syncthreads();
    if (t < 200) {
        const int r  = t / 25;
        const int c4 = (t - r * 25) * 4;
        float acc0 = bs[c4 + 0], acc1 = bs[c4 + 1], acc2 = bs[c4 + 2], acc3 = bs[c4 + 3];
        for (int k = 0; k < DIM; ++k) {
            const float xv = xs[r][k];
            const float4 wv = *reinterpret_cast<const float4*>(&Wt[k][c4]);
            acc0 += xv * wv.x; acc1 += xv * wv.y; acc2 += xv * wv.z; acc3 += xv * wv.w;
        }
        const int row = row0 + r;
        if (row < N_NODES)
            *reinterpret_cast<float4*>(&hidden[row * DIM + c4]) =
                make_float4(acc0, acc1, acc2, acc3);
    }
}

__global__ __launch_bounds__(256) void srgnn_scatter_atomic(
    const float* __restrict__ hidden, const int* __restrict__ esrc,
    const int* __restrict__ edst, const float* __restrict__ ew,
    float* __restrict__ out)
{
    const unsigned gid = blockIdx.x * 256u + threadIdx.x;
    const unsigned e = gid / 25u;
    const unsigned j = gid - e * 25u;
    if (e >= N_EDGES) return;
    const int   s  = esrc[e];
    const int   d  = edst[e];
    const float wt = ew[e];
    const float4 h = *reinterpret_cast<const float4*>(&hidden[(size_t)s * DIM + j * 4]);
    float* op = &out[(size_t)d * DIM + j * 4];
    atomicAdd(op + 0, h.x * wt);
    atomicAdd(op + 1, h.y * wt);
    atomicAdd(op + 2, h.z * wt);
    atomicAdd(op + 3, h.w * wt);
}

extern "C" void kernel_launch(void* const* d_in, const int* in_sizes, int n_in,
                              void* d_out, int out_size, void* d_ws, size_t ws_size,
                              hipStream_t stream) {
    const float* x    = (const float*)d_in[0];
    const int*   esrc = (const int*)  d_in[1];
    const int*   edst = (const int*)  d_in[2];
    const float* ew   = (const float*)d_in[3];
    const float* W    = (const float*)d_in[4];
    const float* b    = (const float*)d_in[5];
    float* out = (float*)d_out;

    char* ws = (char*)d_ws;

    if (ws_size >= WS_NEED) {
        unsigned* hidU = (unsigned*)(ws + HIDB_OFF);
        int*      cnt  = (int*)     (ws + CNT_OFF);
        int*      ovfc = (int*)     (ws + OVFC_OFF);
        int4*     ovf  = (int4*)    (ws + OVF_OFF);
        unsigned* bkt  = (unsigned*)(ws + BKT_OFF);
        float*    Wt   = (float*)   (ws + WT_OFF);

        // GEMM: hidden(bf16) = x @ W^T + b
        srgnn_transpose<<<(DIM * DIM + 255) / 256, 256, 0, stream>>>(W, Wt);
        srgnn_gemm2b<<<N_NODES / ROWS_PB, 256, 0, stream>>>(x, Wt, b, hidU);

        // zero cnt + ovf counter (contiguous), then single-pass bucket scatter
        hipMemsetAsync(cnt, 0, N_NODES * sizeof(int) + 16, stream);
        const int eblocks = (N_EDGES + 255) / 256;
        srgnn_bucket4<<<eblocks, 256, 0, stream>>>(esrc, edst, ew, cnt, ovfc, ovf, bkt);

        // aggregate: one wave per node, plain stores
        const int agg_blocks = (N_NODES + 3) / 4;
        srgnn_agg_p4<<<agg_blocks, 256, 0, stream>>>(hidU, cnt, bkt, ovfc, ovf, out);
    } else {
        // fallback: atomic scatter
        float* hidden = (float*)ws;
        hipMemsetAsync(d_out, 0, (size_t)out_size * sizeof(float), stream);
        const int gemm_blocks = (N_NODES + 7) / 8;
        srgnn_gemm_bias<<<gemm_blocks, 256, 0, stream>>>(x, W, b, hidden);
        const long long work = (long long)N_EDGES * 25;
        const int scat_blocks = (int)((work + 255) / 256);
        srgnn_scatter_atomic<<<scat_blocks, 256, 0, stream>>>(hidden, esrc, edst, ew, out);
    }
}

// Round 7
// 94.786 us; speedup vs baseline: 13.6780x; 1.3883x over previous
//
#include <hip/hip_runtime.h>

#define N_NODES 50000
#define N_EDGES 800000
#define DIM 100

#define NB      391         // coarse buckets of 128 nodes: ceil(50000/128)
#define CAPB    2816        // records per bucket region (mean 2046, sigma 45)
#define OVF_CAP 4096

// ---------------- workspace layout (bytes) ----------------
#define HIDB_OFF  0u            // bf16 hidden, packed uint[50000*50]   10,000,000
#define GCUR_OFF  10000000u     // int gcur[391] bucket cursors               1,600
#define OVFC_OFF  10001600u     // int ovf_cnt (+pad)                            16
#define OVF_OFF   10001616u     // int4 ovf[4096]                            65,536
#define BKT2_OFF  10067152u     // uint2 bkt2[391*2816]                   8,808,448
#define WT_OFF    18875600u     // float Wt[100*100]                         40,000
#define WS_NEED   18915600u

#define ROWS_PB 40              // gemm rows per block (50000/40 = 1250 exact)

// float->bf16 RNE helpers
__device__ inline unsigned bf16hi(float v) {            // bf16 in HIGH 16 bits
    unsigned u = __float_as_uint(v);
    u += 0x7FFFu + ((u >> 16) & 1u);
    return u & 0xFFFF0000u;
}
__device__ inline unsigned bf16pair(float lo, float hi) {
    unsigned ulo = __float_as_uint(lo); ulo += 0x7FFFu + ((ulo >> 16) & 1u);
    unsigned uhi = __float_as_uint(hi); uhi += 0x7FFFu + ((uhi >> 16) & 1u);
    return (ulo >> 16) | (uhi & 0xFFFF0000u);
}

// ---------------- transpose + control-buffer zeroing ----------------
__global__ __launch_bounds__(256) void srgnn_transpose(
    const float* __restrict__ W, float* __restrict__ Wt,
    int* __restrict__ gcur, int* __restrict__ ovfc)
{
    const unsigned i = blockIdx.x * 256u + threadIdx.x;
    if (i < DIM * DIM) {
        const int c = i / DIM, k = i - c * DIM;
        Wt[k * DIM + c] = W[i];
    }
    if (i < NB) gcur[i] = 0;
    if (i == 0) *ovfc = 0;
}

// ---------------- GEMM: hidden(bf16) = x @ W^T + b ----------------
__global__ __launch_bounds__(256) void srgnn_gemm2b(
    const float* __restrict__ x, const float* __restrict__ Wt,
    const float* __restrict__ b, unsigned* __restrict__ hidU)
{
    __shared__ float xs[ROWS_PB][DIM];   // 16 KB
    const int t = threadIdx.x;
    const int row0 = blockIdx.x * ROWS_PB;

    for (int i = t; i < ROWS_PB * 25; i += 256) {
        const int r = i / 25, c4 = (i - r * 25) * 4;
        const float4 v = *reinterpret_cast<const float4*>(
            &x[(size_t)(row0 + r) * DIM + c4]);
        *reinterpret_cast<float4*>(&xs[r][c4]) = v;
    }
    __syncthreads();

    if (t < 250) {
        const int g  = t / 25;            // row group 0..9
        const int c4 = (t - g * 25) * 4;  // col chunk
        const float4 bv = *reinterpret_cast<const float4*>(&b[c4]);
        float4 a0 = bv, a1 = bv, a2 = bv, a3 = bv;

        #pragma unroll 4
        for (int k = 0; k < DIM; ++k) {
            const float4 wv = *reinterpret_cast<const float4*>(&Wt[k * DIM + c4]);
            const float x0 = xs[g     ][k];
            const float x1 = xs[g + 10][k];
            const float x2 = xs[g + 20][k];
            const float x3 = xs[g + 30][k];
            a0.x += x0 * wv.x; a0.y += x0 * wv.y; a0.z += x0 * wv.z; a0.w += x0 * wv.w;
            a1.x += x1 * wv.x; a1.y += x1 * wv.y; a1.z += x1 * wv.z; a1.w += x1 * wv.w;
            a2.x += x2 * wv.x; a2.y += x2 * wv.y; a2.z += x2 * wv.z; a2.w += x2 * wv.w;
            a3.x += x3 * wv.x; a3.y += x3 * wv.y; a3.z += x3 * wv.z; a3.w += x3 * wv.w;
        }
        const int u0 = c4 >> 1;           // uint index within row (50 uints/row)
        uint2 p;
        p.x = bf16pair(a0.x, a0.y); p.y = bf16pair(a0.z, a0.w);
        *reinterpret_cast<uint2*>(&hidU[(size_t)(row0 + g     ) * 50 + u0]) = p;
        p.x = bf16pair(a1.x, a1.y); p.y = bf16pair(a1.z, a1.w);
        *reinterpret_cast<uint2*>(&hidU[(size_t)(row0 + g + 10) * 50 + u0]) = p;
        p.x = bf16pair(a2.x, a2.y); p.y = bf16pair(a2.z, a2.w);
        *reinterpret_cast<uint2*>(&hidU[(size_t)(row0 + g + 20) * 50 + u0]) = p;
        p.x = bf16pair(a3.x, a3.y); p.y = bf16pair(a3.z, a3.w);
        *reinterpret_cast<uint2*>(&hidU[(size_t)(row0 + g + 30) * 50 + u0]) = p;
    }
}

// ---------------- bin: edges -> coarse buckets (contiguous runs) ----------
// Per block: LDS hist over 391 buckets, ONE global atomicAdd per
// (block,bucket) reserves a contiguous run, records written back-to-back
// -> same-line stores are temporally local -> L2 absorbs the writebacks.
__global__ __launch_bounds__(512) void srgnn_bin(
    const int* __restrict__ esrc, const int* __restrict__ edst,
    const float* __restrict__ ew, int* __restrict__ gcur,
    int* __restrict__ ovfc, int4* __restrict__ ovf, uint2* __restrict__ bkt2)
{
    __shared__ int hist[NB];
    __shared__ int lcur[NB];
    const int t = threadIdx.x;
    const int e0 = blockIdx.x * 2048;

    for (int i = t; i < NB; i += 512) hist[i] = 0;
    __syncthreads();

    int d[4];
    #pragma unroll
    for (int k = 0; k < 4; ++k) {
        const int e = e0 + t + k * 512;
        d[k] = (e < N_EDGES) ? edst[e] : -1;
        if (d[k] >= 0) atomicAdd(&hist[d[k] >> 7], 1);
    }
    __syncthreads();
    for (int i = t; i < NB; i += 512) lcur[i] = atomicAdd(&gcur[i], hist[i]);
    __syncthreads();
    #pragma unroll
    for (int k = 0; k < 4; ++k) {
        if (d[k] >= 0) {
            const int e = e0 + t + k * 512;
            const int s = esrc[e];
            const float w = ew[e];
            const int bq = d[k] >> 7;
            const int pos = atomicAdd(&lcur[bq], 1);
            if (pos < CAPB) {
                bkt2[(size_t)bq * CAPB + pos] =
                    make_uint2((unsigned)s | bf16hi(w), (unsigned)d[k]);
            } else {
                const int op = atomicAdd(ovfc, 1);
                if (op < OVF_CAP) ovf[op] = make_int4(d[k], s, __float_as_int(w), 0);
            }
        }
    }
}

// ---------------- aggregate: block per bucket, LDS counting sort ----------
// Stage ~2046 records coalesced, LDS-sort by local node (hist + scan +
// place), then wave-per-node: records via LDS broadcast, bf16 row gathers
// 4-deep, f32 register accumulate, plain float2 store.
__global__ __launch_bounds__(1024) void srgnn_agg_s(
    const unsigned* __restrict__ hidU, const int* __restrict__ gcur,
    const uint2* __restrict__ bkt2, const int* __restrict__ ovfc,
    const int4* __restrict__ ovf, float* __restrict__ out)
{
    __shared__ uint2    recs[CAPB];     // 22528 B
    __shared__ unsigned srt[CAPB];      // 11264 B
    __shared__ int nh[128], sc[128], cur[128];

    const int t = threadIdx.x;
    const int bq = blockIdx.x;
    int cntb = gcur[bq];
    if (cntb > CAPB) cntb = CAPB;

    if (t < 128) nh[t] = 0;
    __syncthreads();
    for (int i = t; i < cntb; i += 1024) {
        const uint2 r = bkt2[(size_t)bq * CAPB + i];
        recs[i] = r;
        atomicAdd(&nh[r.y & 127], 1);
    }
    __syncthreads();
    if (t < 128) sc[t] = nh[t];
    __syncthreads();
    for (int ofs = 1; ofs < 128; ofs <<= 1) {        // Hillis-Steele inclusive
        int a = 0;
        if (t < 128 && t >= ofs) a = sc[t - ofs];
        __syncthreads();
        if (t < 128) sc[t] += a;
        __syncthreads();
    }
    if (t < 128) cur[t] = sc[t] - nh[t];
    __syncthreads();
    for (int i = t; i < cntb; i += 1024) {
        const uint2 r = recs[i];
        const int pos = atomicAdd(&cur[r.y & 127], 1);
        srt[pos] = r.x;                              // src | bf16(w)<<16
    }
    __syncthreads();

    int oc = *ovfc;                                  // ~always 0
    if (oc > OVF_CAP) oc = OVF_CAP;
    const int lane = t & 63;
    const int wid  = t >> 6;
    const bool active = (lane < 50);

    for (int q = 0; q < 8; ++q) {
        const int n  = wid * 8 + q;
        const int s1 = sc[n];
        const int s0 = s1 - nh[n];
        float2 acc = make_float2(0.f, 0.f);

        int p = s0;
        for (; p + 4 <= s1; p += 4) {
            const unsigned r0 = srt[p + 0];          // LDS broadcast reads
            const unsigned r1 = srt[p + 1];
            const unsigned r2 = srt[p + 2];
            const unsigned r3 = srt[p + 3];
            const float w0 = __uint_as_float(r0 & 0xFFFF0000u);
            const float w1 = __uint_as_float(r1 & 0xFFFF0000u);
            const float w2 = __uint_as_float(r2 & 0xFFFF0000u);
            const float w3 = __uint_as_float(r3 & 0xFFFF0000u);
            if (active) {
                const unsigned h0 = hidU[(size_t)(r0 & 0xFFFFu) * 50 + lane];
                const unsigned h1 = hidU[(size_t)(r1 & 0xFFFFu) * 50 + lane];
                const unsigned h2 = hidU[(size_t)(r2 & 0xFFFFu) * 50 + lane];
                const unsigned h3 = hidU[(size_t)(r3 & 0xFFFFu) * 50 + lane];
                acc.x += w0 * __uint_as_float(h0 << 16);
                acc.y += w0 * __uint_as_float(h0 & 0xFFFF0000u);
                acc.x += w1 * __uint_as_float(h1 << 16);
                acc.y += w1 * __uint_as_float(h1 & 0xFFFF0000u);
                acc.x += w2 * __uint_as_float(h2 << 16);
                acc.y += w2 * __uint_as_float(h2 & 0xFFFF0000u);
                acc.x += w3 * __uint_as_float(h3 << 16);
                acc.y += w3 * __uint_as_float(h3 & 0xFFFF0000u);
            }
        }
        for (; p < s1; ++p) {
            const unsigned r = srt[p];
            const float wi = __uint_as_float(r & 0xFFFF0000u);
            if (active) {
                const unsigned h = hidU[(size_t)(r & 0xFFFFu) * 50 + lane];
                acc.x += wi * __uint_as_float(h << 16);
                acc.y += wi * __uint_as_float(h & 0xFFFF0000u);
            }
        }

        const int ng = bq * 128 + n;
        if (oc > 0) {                                // ultra-rare overflow scan
            for (int i = 0; i < oc; ++i) {
                const int4 v = ovf[i];
                if (v.x == ng && active) {
                    const unsigned h = hidU[(size_t)v.y * 50 + lane];
                    const float wi = __int_as_float(v.z);
                    acc.x += wi * __uint_as_float(h << 16);
                    acc.y += wi * __uint_as_float(h & 0xFFFF0000u);
                }
            }
        }
        if (ng < N_NODES && active)
            *reinterpret_cast<float2*>(&out[(size_t)ng * DIM + 2 * lane]) = acc;
    }
}

// ---------------- fallback (atomic scatter, needs only 20MB ws) ----------
__global__ __launch_bounds__(256) void srgnn_gemm_bias(
    const float* __restrict__ x, const float* __restrict__ W,
    const float* __restrict__ b, float* __restrict__ hidden)
{
    __shared__ float Wt[DIM][DIM + 4];
    __shared__ float bs[DIM];
    __shared__ float xs[8][DIM];
    const int t = threadIdx.x;
    for (int i = t; i < DIM * DIM; i += 256) {
        int c = i / DIM, k = i - c * DIM;
        Wt[k][c] = W[i];
    }
    if (t < DIM) bs[t] = b[t];
    const int row0 = blockIdx.x * 8;
    for (int i = t; i < 8 * DIM; i += 256) {
        int r = i / DIM, k = i - r * DIM;
        int row = row0 + r;
        xs[r][k] = (row < N_NODES) ? x[row * DIM + k] : 0.0f;
    }
    __syncthreads();
    if (t < 200) {
        const int r  = t / 25;
        const int c4 = (t - r * 25) * 4;
        float acc0 = bs[c4 + 0], acc1 = bs[c4 + 1], acc2 = bs[c4 + 2], acc3 = bs[c4 + 3];
        for (int k = 0; k < DIM; ++k) {
            const float xv = xs[r][k];
            const float4 wv = *reinterpret_cast<const float4*>(&Wt[k][c4]);
            acc0 += xv * wv.x; acc1 += xv * wv.y; acc2 += xv * wv.z; acc3 += xv * wv.w;
        }
        const int row = row0 + r;
        if (row < N_NODES)
            *reinterpret_cast<float4*>(&hidden[row * DIM + c4]) =
                make_float4(acc0, acc1, acc2, acc3);
    }
}

__global__ __launch_bounds__(256) void srgnn_scatter_atomic(
    const float* __restrict__ hidden, const int* __restrict__ esrc,
    const int* __restrict__ edst, const float* __restrict__ ew,
    float* __restrict__ out)
{
    const unsigned gid = blockIdx.x * 256u + threadIdx.x;
    const unsigned e = gid / 25u;
    const unsigned j = gid - e * 25u;
    if (e >= N_EDGES) return;
    const int   s  = esrc[e];
    const int   d  = edst[e];
    const float wt = ew[e];
    const float4 h = *reinterpret_cast<const float4*>(&hidden[(size_t)s * DIM + j * 4]);
    float* op = &out[(size_t)d * DIM + j * 4];
    atomicAdd(op + 0, h.x * wt);
    atomicAdd(op + 1, h.y * wt);
    atomicAdd(op + 2, h.z * wt);
    atomicAdd(op + 3, h.w * wt);
}

extern "C" void kernel_launch(void* const* d_in, const int* in_sizes, int n_in,
                              void* d_out, int out_size, void* d_ws, size_t ws_size,
                              hipStream_t stream) {
    const float* x    = (const float*)d_in[0];
    const int*   esrc = (const int*)  d_in[1];
    const int*   edst = (const int*)  d_in[2];
    const float* ew   = (const float*)d_in[3];
    const float* W    = (const float*)d_in[4];
    const float* b    = (const float*)d_in[5];
    float* out = (float*)d_out;

    char* ws = (char*)d_ws;

    if (ws_size >= WS_NEED) {
        unsigned* hidU = (unsigned*)(ws + HIDB_OFF);
        int*      gcur = (int*)     (ws + GCUR_OFF);
        int*      ovfc = (int*)     (ws + OVFC_OFF);
        int4*     ovf  = (int4*)    (ws + OVF_OFF);
        uint2*    bkt2 = (uint2*)   (ws + BKT2_OFF);
        float*    Wt   = (float*)   (ws + WT_OFF);

        // transpose W + zero control buffers (one dispatch)
        srgnn_transpose<<<(DIM * DIM + 255) / 256, 256, 0, stream>>>(W, Wt, gcur, ovfc);
        // GEMM: hidden(bf16) = x @ W^T + b
        srgnn_gemm2b<<<N_NODES / ROWS_PB, 256, 0, stream>>>(x, Wt, b, hidU);
        // bin edges into coarse buckets (contiguous runs)
        srgnn_bin<<<(N_EDGES + 2047) / 2048, 512, 0, stream>>>(
            esrc, edst, ew, gcur, ovfc, ovf, bkt2);
        // block-per-bucket LDS sort + aggregate
        srgnn_agg_s<<<NB, 1024, 0, stream>>>(hidU, gcur, bkt2, ovfc, ovf, out);
    } else {
        // fallback: atomic scatter
        float* hidden = (float*)ws;
        hipMemsetAsync(d_out, 0, (size_t)out_size * sizeof(float), stream);
        const int gemm_blocks = (N_NODES + 7) / 8;
        srgnn_gemm_bias<<<gemm_blocks, 256, 0, stream>>>(x, W, b, hidden);
        const long long work = (long long)N_EDGES * 25;
        const int scat_blocks = (int)((work + 255) / 256);
        srgnn_scatter_atomic<<<scat_blocks, 256, 0, stream>>>(hidden, esrc, edst, ew, out);
    }
}

// Round 8
// 92.407 us; speedup vs baseline: 14.0301x; 1.0257x over previous
//
#include <hip/hip_runtime.h>

#define N_NODES 50000
#define N_EDGES 800000
#define DIM 100

#define NB      782         // coarse buckets of 64 nodes: ceil(50000/64)
#define CAPB    1280        // records per bucket region (mean 1024, +8 sigma)
#define OVF_CAP 4096
#define EPB     4096        // edges per bin block

// ---------------- workspace layout (bytes) ----------------
#define HIDB_OFF  0u            // bf16 hidden, packed uint[50000*50]   10,000,000
#define GCUR_OFF  10000000u     // int gcur[782] bucket cursors               3,128
#define OVFC_OFF  10003128u     // int ovf_cnt (+pad to 16B align)               24
#define OVF_OFF   10003152u     // int4 ovf[4096] (16B-aligned)              65,536
#define BKT2_OFF  10068736u     // uint2 bkt2[782*1280] (128B-aligned)    8,007,680
#define WT_OFF    18076416u     // float Wt[100*100]                         40,000
#define WS_NEED   18116416u

#define ROWS_PB 40              // gemm rows per block (50000/40 = 1250 exact)

// float->bf16 RNE helpers
__device__ inline unsigned bf16hi(float v) {            // bf16 in HIGH 16 bits
    unsigned u = __float_as_uint(v);
    u += 0x7FFFu + ((u >> 16) & 1u);
    return u & 0xFFFF0000u;
}
__device__ inline unsigned bf16pair(float lo, float hi) {
    unsigned ulo = __float_as_uint(lo); ulo += 0x7FFFu + ((ulo >> 16) & 1u);
    unsigned uhi = __float_as_uint(hi); uhi += 0x7FFFu + ((uhi >> 16) & 1u);
    return (ulo >> 16) | (uhi & 0xFFFF0000u);
}

// ---------------- transpose + control-buffer zeroing ----------------
__global__ __launch_bounds__(256) void srgnn_transpose(
    const float* __restrict__ W, float* __restrict__ Wt,
    int* __restrict__ gcur, int* __restrict__ ovfc)
{
    const unsigned i = blockIdx.x * 256u + threadIdx.x;
    if (i < DIM * DIM) {
        const int c = i / DIM, k = i - c * DIM;
        Wt[k * DIM + c] = W[i];
    }
    if (i < NB) gcur[i] = 0;
    if (i == 0) *ovfc = 0;
}

// ---------------- GEMM: hidden(bf16) = x @ W^T + b ----------------
__global__ __launch_bounds__(256) void srgnn_gemm2b(
    const float* __restrict__ x, const float* __restrict__ Wt,
    const float* __restrict__ b, unsigned* __restrict__ hidU)
{
    __shared__ float xs[ROWS_PB][DIM];   // 16 KB
    const int t = threadIdx.x;
    const int row0 = blockIdx.x * ROWS_PB;

    for (int i = t; i < ROWS_PB * 25; i += 256) {
        const int r = i / 25, c4 = (i - r * 25) * 4;
        const float4 v = *reinterpret_cast<const float4*>(
            &x[(size_t)(row0 + r) * DIM + c4]);
        *reinterpret_cast<float4*>(&xs[r][c4]) = v;
    }
    __syncthreads();

    if (t < 250) {
        const int g  = t / 25;            // row group 0..9
        const int c4 = (t - g * 25) * 4;  // col chunk
        const float4 bv = *reinterpret_cast<const float4*>(&b[c4]);
        float4 a0 = bv, a1 = bv, a2 = bv, a3 = bv;

        #pragma unroll 4
        for (int k = 0; k < DIM; ++k) {
            const float4 wv = *reinterpret_cast<const float4*>(&Wt[k * DIM + c4]);
            const float x0 = xs[g     ][k];
            const float x1 = xs[g + 10][k];
            const float x2 = xs[g + 20][k];
            const float x3 = xs[g + 30][k];
            a0.x += x0 * wv.x; a0.y += x0 * wv.y; a0.z += x0 * wv.z; a0.w += x0 * wv.w;
            a1.x += x1 * wv.x; a1.y += x1 * wv.y; a1.z += x1 * wv.z; a1.w += x1 * wv.w;
            a2.x += x2 * wv.x; a2.y += x2 * wv.y; a2.z += x2 * wv.z; a2.w += x2 * wv.w;
            a3.x += x3 * wv.x; a3.y += x3 * wv.y; a3.z += x3 * wv.z; a3.w += x3 * wv.w;
        }
        const int u0 = c4 >> 1;           // uint index within row (50 uints/row)
        uint2 p;
        p.x = bf16pair(a0.x, a0.y); p.y = bf16pair(a0.z, a0.w);
        *reinterpret_cast<uint2*>(&hidU[(size_t)(row0 + g     ) * 50 + u0]) = p;
        p.x = bf16pair(a1.x, a1.y); p.y = bf16pair(a1.z, a1.w);
        *reinterpret_cast<uint2*>(&hidU[(size_t)(row0 + g + 10) * 50 + u0]) = p;
        p.x = bf16pair(a2.x, a2.y); p.y = bf16pair(a2.z, a2.w);
        *reinterpret_cast<uint2*>(&hidU[(size_t)(row0 + g + 20) * 50 + u0]) = p;
        p.x = bf16pair(a3.x, a3.y); p.y = bf16pair(a3.z, a3.w);
        *reinterpret_cast<uint2*>(&hidU[(size_t)(row0 + g + 30) * 50 + u0]) = p;
    }
}

// ---------------- bin: edges -> coarse buckets (contiguous runs) ----------
// Per block: LDS hist over 782 buckets, ONE global atomicAdd per nonzero
// (block,bucket) reserves a contiguous run, records written back-to-back
// -> same-line stores are temporally local -> L2 absorbs the writebacks.
__global__ __launch_bounds__(512) void srgnn_bin(
    const int* __restrict__ esrc, const int* __restrict__ edst,
    const float* __restrict__ ew, int* __restrict__ gcur,
    int* __restrict__ ovfc, int4* __restrict__ ovf, uint2* __restrict__ bkt2)
{
    __shared__ int hist[NB];
    __shared__ int lcur[NB];
    const int t = threadIdx.x;
    const int e0 = blockIdx.x * EPB;

    for (int i = t; i < NB; i += 512) hist[i] = 0;
    __syncthreads();

    int d[8];
    #pragma unroll
    for (int k = 0; k < 8; ++k) {
        const int e = e0 + t + k * 512;
        d[k] = (e < N_EDGES) ? edst[e] : -1;
        if (d[k] >= 0) atomicAdd(&hist[d[k] >> 6], 1);
    }
    __syncthreads();
    for (int i = t; i < NB; i += 512)
        if (hist[i]) lcur[i] = atomicAdd(&gcur[i], hist[i]);
    __syncthreads();
    #pragma unroll
    for (int k = 0; k < 8; ++k) {
        if (d[k] >= 0) {
            const int e = e0 + t + k * 512;
            const int s = esrc[e];
            const float w = ew[e];
            const int bq = d[k] >> 6;
            const int pos = atomicAdd(&lcur[bq], 1);
            if (pos < CAPB) {
                bkt2[(size_t)bq * CAPB + pos] =
                    make_uint2((unsigned)s | bf16hi(w), (unsigned)d[k]);
            } else {
                const int op = atomicAdd(ovfc, 1);
                if (op < OVF_CAP) ovf[op] = make_int4(d[k], s, __float_as_int(w), 0);
            }
        }
    }
}

// ---------------- aggregate: block per 64-node bucket, LDS counting sort --
// 512 thr / 8 waves / ~16 KB LDS -> 4 blocks/CU (full 32-wave occupancy).
// Stage ~1024 records coalesced, LDS-sort by local node (hist + scan +
// place), then wave-per-node x8: records via LDS broadcast, bf16 row
// gathers 4-deep, f32 register accumulate, plain float2 store.
__global__ __launch_bounds__(512) void srgnn_agg_s64(
    const unsigned* __restrict__ hidU, const int* __restrict__ gcur,
    const uint2* __restrict__ bkt2, const int* __restrict__ ovfc,
    const int4* __restrict__ ovf, float* __restrict__ out)
{
    __shared__ uint2    recs[CAPB];     // 10240 B
    __shared__ unsigned srt[CAPB];      //  5120 B
    __shared__ int nh[64], sc[64], cur[64];

    const int t = threadIdx.x;
    const int bq = blockIdx.x;
    int cntb = gcur[bq];
    if (cntb > CAPB) cntb = CAPB;

    if (t < 64) nh[t] = 0;
    __syncthreads();
    for (int i = t; i < cntb; i += 512) {
        const uint2 r = bkt2[(size_t)bq * CAPB + i];
        recs[i] = r;
        atomicAdd(&nh[r.y & 63], 1);
    }
    __syncthreads();
    if (t < 64) sc[t] = nh[t];
    __syncthreads();
    for (int ofs = 1; ofs < 64; ofs <<= 1) {         // Hillis-Steele inclusive
        int a = 0;
        if (t < 64 && t >= ofs) a = sc[t - ofs];
        __syncthreads();
        if (t < 64) sc[t] += a;
        __syncthreads();
    }
    if (t < 64) cur[t] = sc[t] - nh[t];
    __syncthreads();
    for (int i = t; i < cntb; i += 512) {
        const uint2 r = recs[i];
        const int pos = atomicAdd(&cur[r.y & 63], 1);
        srt[pos] = r.x;                              // src | bf16(w)<<16
    }
    __syncthreads();

    int oc = *ovfc;                                  // ~always 0
    if (oc > OVF_CAP) oc = OVF_CAP;
    const int lane = t & 63;
    const int wid  = t >> 6;                         // 8 waves
    const bool active = (lane < 50);

    for (int q = 0; q < 8; ++q) {
        const int n  = wid * 8 + q;                  // 8 waves x 8 = 64 nodes
        const int s1 = sc[n];
        const int s0 = s1 - nh[n];
        float2 acc = make_float2(0.f, 0.f);

        int p = s0;
        for (; p + 4 <= s1; p += 4) {
            const unsigned r0 = srt[p + 0];          // LDS broadcast reads
            const unsigned r1 = srt[p + 1];
            const unsigned r2 = srt[p + 2];
            const unsigned r3 = srt[p + 3];
            const float w0 = __uint_as_float(r0 & 0xFFFF0000u);
            const float w1 = __uint_as_float(r1 & 0xFFFF0000u);
            const float w2 = __uint_as_float(r2 & 0xFFFF0000u);
            const float w3 = __uint_as_float(r3 & 0xFFFF0000u);
            if (active) {
                const unsigned h0 = hidU[(size_t)(r0 & 0xFFFFu) * 50 + lane];
                const unsigned h1 = hidU[(size_t)(r1 & 0xFFFFu) * 50 + lane];
                const unsigned h2 = hidU[(size_t)(r2 & 0xFFFFu) * 50 + lane];
                const unsigned h3 = hidU[(size_t)(r3 & 0xFFFFu) * 50 + lane];
                acc.x += w0 * __uint_as_float(h0 << 16);
                acc.y += w0 * __uint_as_float(h0 & 0xFFFF0000u);
                acc.x += w1 * __uint_as_float(h1 << 16);
                acc.y += w1 * __uint_as_float(h1 & 0xFFFF0000u);
                acc.x += w2 * __uint_as_float(h2 << 16);
                acc.y += w2 * __uint_as_float(h2 & 0xFFFF0000u);
                acc.x += w3 * __uint_as_float(h3 << 16);
                acc.y += w3 * __uint_as_float(h3 & 0xFFFF0000u);
            }
        }
        for (; p < s1; ++p) {
            const unsigned r = srt[p];
            const float wi = __uint_as_float(r & 0xFFFF0000u);
            if (active) {
                const unsigned h = hidU[(size_t)(r & 0xFFFFu) * 50 + lane];
                acc.x += wi * __uint_as_float(h << 16);
                acc.y += wi * __uint_as_float(h & 0xFFFF0000u);
            }
        }

        const int ng = bq * 64 + n;
        if (oc > 0) {                                // ultra-rare overflow scan
            for (int i = 0; i < oc; ++i) {
                const int4 v = ovf[i];
                if (v.x == ng && active) {
                    const unsigned h = hidU[(size_t)v.y * 50 + lane];
                    const float wi = __int_as_float(v.z);
                    acc.x += wi * __uint_as_float(h << 16);
                    acc.y += wi * __uint_as_float(h & 0xFFFF0000u);
                }
            }
        }
        if (ng < N_NODES && active)
            *reinterpret_cast<float2*>(&out[(size_t)ng * DIM + 2 * lane]) = acc;
    }
}

// ---------------- fallback (atomic scatter, needs only 20MB ws) ----------
__global__ __launch_bounds__(256) void srgnn_gemm_bias(
    const float* __restrict__ x, const float* __restrict__ W,
    const float* __restrict__ b, float* __restrict__ hidden)
{
    __shared__ float Wt[DIM][DIM + 4];
    __shared__ float bs[DIM];
    __shared__ float xs[8][DIM];
    const int t = threadIdx.x;
    for (int i = t; i < DIM * DIM; i += 256) {
        int c = i / DIM, k = i - c * DIM;
        Wt[k][c] = W[i];
    }
    if (t < DIM) bs[t] = b[t];
    const int row0 = blockIdx.x * 8;
    for (int i = t; i < 8 * DIM; i += 256) {
        int r = i / DIM, k = i - r * DIM;
        int row = row0 + r;
        xs[r][k] = (row < N_NODES) ? x[row * DIM + k] : 0.0f;
    }
    __syncthreads();
    if (t < 200) {
        const int r  = t / 25;
        const int c4 = (t - r * 25) * 4;
        float acc0 = bs[c4 + 0], acc1 = bs[c4 + 1], acc2 = bs[c4 + 2], acc3 = bs[c4 + 3];
        for (int k = 0; k < DIM; ++k) {
            const float xv = xs[r][k];
            const float4 wv = *reinterpret_cast<const float4*>(&Wt[k][c4]);
            acc0 += xv * wv.x; acc1 += xv * wv.y; acc2 += xv * wv.z; acc3 += xv * wv.w;
        }
        const int row = row0 + r;
        if (row < N_NODES)
            *reinterpret_cast<float4*>(&hidden[row * DIM + c4]) =
                make_float4(acc0, acc1, acc2, acc3);
    }
}

__global__ __launch_bounds__(256) void srgnn_scatter_atomic(
    const float* __restrict__ hidden, const int* __restrict__ esrc,
    const int* __restrict__ edst, const float* __restrict__ ew,
    float* __restrict__ out)
{
    const unsigned gid = blockIdx.x * 256u + threadIdx.x;
    const unsigned e = gid / 25u;
    const unsigned j = gid - e * 25u;
    if (e >= N_EDGES) return;
    const int   s  = esrc[e];
    const int   d  = edst[e];
    const float wt = ew[e];
    const float4 h = *reinterpret_cast<const float4*>(&hidden[(size_t)s * DIM + j * 4]);
    float* op = &out[(size_t)d * DIM + j * 4];
    atomicAdd(op + 0, h.x * wt);
    atomicAdd(op + 1, h.y * wt);
    atomicAdd(op + 2, h.z * wt);
    atomicAdd(op + 3, h.w * wt);
}

extern "C" void kernel_launch(void* const* d_in, const int* in_sizes, int n_in,
                              void* d_out, int out_size, void* d_ws, size_t ws_size,
                              hipStream_t stream) {
    const float* x    = (const float*)d_in[0];
    const int*   esrc = (const int*)  d_in[1];
    const int*   edst = (const int*)  d_in[2];
    const float* ew   = (const float*)d_in[3];
    const float* W    = (const float*)d_in[4];
    const float* b    = (const float*)d_in[5];
    float* out = (float*)d_out;

    char* ws = (char*)d_ws;

    if (ws_size >= WS_NEED) {
        unsigned* hidU = (unsigned*)(ws + HIDB_OFF);
        int*      gcur = (int*)     (ws + GCUR_OFF);
        int*      ovfc = (int*)     (ws + OVFC_OFF);
        int4*     ovf  = (int4*)    (ws + OVF_OFF);
        uint2*    bkt2 = (uint2*)   (ws + BKT2_OFF);
        float*    Wt   = (float*)   (ws + WT_OFF);

        // transpose W + zero control buffers (one dispatch)
        srgnn_transpose<<<(DIM * DIM + 255) / 256, 256, 0, stream>>>(W, Wt, gcur, ovfc);
        // GEMM: hidden(bf16) = x @ W^T + b
        srgnn_gemm2b<<<N_NODES / ROWS_PB, 256, 0, stream>>>(x, Wt, b, hidU);
        // bin edges into coarse 64-node buckets (contiguous runs)
        srgnn_bin<<<(N_EDGES + EPB - 1) / EPB, 512, 0, stream>>>(
            esrc, edst, ew, gcur, ovfc, ovf, bkt2);
        // block-per-bucket LDS sort + aggregate
        srgnn_agg_s64<<<NB, 512, 0, stream>>>(hidU, gcur, bkt2, ovfc, ovf, out);
    } else {
        // fallback: atomic scatter
        float* hidden = (float*)ws;
        hipMemsetAsync(d_out, 0, (size_t)out_size * sizeof(float), stream);
        const int gemm_blocks = (N_NODES + 7) / 8;
        srgnn_gemm_bias<<<gemm_blocks, 256, 0, stream>>>(x, W, b, hidden);
        const long long work = (long long)N_EDGES * 25;
        const int scat_blocks = (int)((work + 255) / 256);
        srgnn_scatter_atomic<<<scat_blocks, 256, 0, stream>>>(hidden, esrc, edst, ew, out);
    }
}

// Round 9
// 72.897 us; speedup vs baseline: 17.7852x; 1.2676x over previous
//
#include <hip/hip_runtime.h>

#define N_NODES 50000
#define N_EDGES 800000
#define DIM 100

#define NB      1563        // coarse buckets of 32 nodes: ceil(50000/32)
#define CAPB    768         // records per bucket region (mean 512, +11 sigma)
#define OVF_CAP 4096
#define EPB     8192        // edges per bin block
#define GEMM_BLOCKS 625     // 50000 / 80
#define BIN_BLOCKS  98      // ceil(800000 / 8192)
#define ROWS_PB 80          // gemm rows per (512-thread) block

// ---------------- workspace layout (bytes) ----------------
#define HIDB_OFF  0u            // bf16 hidden, packed uint[50000*50]   10,000,000
#define GCUR_OFF  10000000u     // int gcur[1563]                            6,256
#define OVFC_OFF  10006256u     // int ovf_cnt (+pad)                           16
#define OVF_OFF   10006272u     // int4 ovf[4096]                           65,536
#define BKT2_OFF  10071808u     // uint2 bkt2[1563*768] (128B-aligned)   9,603,072
#define WT_OFF    19674880u     // float Wt[100*100]                        40,000
#define WS_NEED   19714880u

// float->bf16 RNE helpers
__device__ inline unsigned bf16hi(float v) {            // bf16 in HIGH 16 bits
    unsigned u = __float_as_uint(v);
    u += 0x7FFFu + ((u >> 16) & 1u);
    return u & 0xFFFF0000u;
}
__device__ inline unsigned bf16pair(float lo, float hi) {
    unsigned ulo = __float_as_uint(lo); ulo += 0x7FFFu + ((ulo >> 16) & 1u);
    unsigned uhi = __float_as_uint(hi); uhi += 0x7FFFu + ((uhi >> 16) & 1u);
    return (ulo >> 16) | (uhi & 0xFFFF0000u);
}

// ---------------- transpose + control-buffer zeroing ----------------
__global__ __launch_bounds__(256) void srgnn_transpose(
    const float* __restrict__ W, float* __restrict__ Wt,
    int* __restrict__ gcur, int* __restrict__ ovfc)
{
    const unsigned i = blockIdx.x * 256u + threadIdx.x;
    if (i < DIM * DIM) {
        const int c = i / DIM, k = i - c * DIM;
        Wt[k * DIM + c] = W[i];
    }
    if (i < NB) gcur[i] = 0;
    if (i == 0) *ovfc = 0;
}

// ---------------- fused GEMM + bin (independent stages, one dispatch) -----
// Blocks [0, GEMM_BLOCKS): hidden(bf16) = x @ W^T + b, 80 rows/block.
// Blocks [GEMM_BLOCKS, +BIN_BLOCKS): bin 8192 edges into 32-node buckets
// via LDS hist + one gcur atomic per (block,bucket) contiguous run.
// All 723 blocks co-resident -> bin's memory/atomic work hides under
// gemm's FMA work.
__global__ __launch_bounds__(512) void srgnn_gemm_bin(
    const float* __restrict__ x, const float* __restrict__ Wt,
    const float* __restrict__ b, unsigned* __restrict__ hidU,
    const int* __restrict__ esrc, const int* __restrict__ edst,
    const float* __restrict__ ew, int* __restrict__ gcur,
    int* __restrict__ ovfc, int4* __restrict__ ovf, uint2* __restrict__ bkt2)
{
    __shared__ __align__(16) char smem[32000];
    const int t = threadIdx.x;

    if (blockIdx.x < GEMM_BLOCKS) {
        // ---------------- GEMM part ----------------
        float (*xs)[DIM] = (float (*)[DIM])smem;     // 80x100 floats = 32000 B
        const int row0 = blockIdx.x * ROWS_PB;

        for (int i = t; i < ROWS_PB * 25; i += 512) {
            const int r = i / 25, c4 = (i - r * 25) * 4;
            const float4 v = *reinterpret_cast<const float4*>(
                &x[(size_t)(row0 + r) * DIM + c4]);
            *reinterpret_cast<float4*>(&xs[r][c4]) = v;
        }
        __syncthreads();

        if (t < 500) {
            const int g  = t / 25;            // row group 0..19
            const int c4 = (t - g * 25) * 4;  // col chunk
            const float4 bv = *reinterpret_cast<const float4*>(&b[c4]);
            float4 a0 = bv, a1 = bv, a2 = bv, a3 = bv;

            #pragma unroll 4
            for (int k = 0; k < DIM; ++k) {
                const float4 wv = *reinterpret_cast<const float4*>(&Wt[k * DIM + c4]);
                const float x0 = xs[g     ][k];
                const float x1 = xs[g + 20][k];
                const float x2 = xs[g + 40][k];
                const float x3 = xs[g + 60][k];
                a0.x += x0 * wv.x; a0.y += x0 * wv.y; a0.z += x0 * wv.z; a0.w += x0 * wv.w;
                a1.x += x1 * wv.x; a1.y += x1 * wv.y; a1.z += x1 * wv.z; a1.w += x1 * wv.w;
                a2.x += x2 * wv.x; a2.y += x2 * wv.y; a2.z += x2 * wv.z; a2.w += x2 * wv.w;
                a3.x += x3 * wv.x; a3.y += x3 * wv.y; a3.z += x3 * wv.z; a3.w += x3 * wv.w;
            }
            const int u0 = c4 >> 1;           // uint index within row
            uint2 p;
            p.x = bf16pair(a0.x, a0.y); p.y = bf16pair(a0.z, a0.w);
            *reinterpret_cast<uint2*>(&hidU[(size_t)(row0 + g     ) * 50 + u0]) = p;
            p.x = bf16pair(a1.x, a1.y); p.y = bf16pair(a1.z, a1.w);
            *reinterpret_cast<uint2*>(&hidU[(size_t)(row0 + g + 20) * 50 + u0]) = p;
            p.x = bf16pair(a2.x, a2.y); p.y = bf16pair(a2.z, a2.w);
            *reinterpret_cast<uint2*>(&hidU[(size_t)(row0 + g + 40) * 50 + u0]) = p;
            p.x = bf16pair(a3.x, a3.y); p.y = bf16pair(a3.z, a3.w);
            *reinterpret_cast<uint2*>(&hidU[(size_t)(row0 + g + 60) * 50 + u0]) = p;
        }
    } else {
        // ---------------- bin part ----------------
        int* hist = (int*)smem;                      // NB ints
        int* lcur = hist + NB;                       // NB ints (12504 B total)
        const int e0 = (blockIdx.x - GEMM_BLOCKS) * EPB;

        for (int i = t; i < NB; i += 512) hist[i] = 0;
        __syncthreads();

        int d[16];
        #pragma unroll
        for (int k = 0; k < 16; ++k) {
            const int e = e0 + t + k * 512;
            d[k] = (e < N_EDGES) ? edst[e] : -1;
            if (d[k] >= 0) atomicAdd(&hist[d[k] >> 5], 1);
        }
        __syncthreads();
        for (int i = t; i < NB; i += 512)
            if (hist[i]) lcur[i] = atomicAdd(&gcur[i], hist[i]);
        __syncthreads();
        #pragma unroll
        for (int k = 0; k < 16; ++k) {
            if (d[k] >= 0) {
                const int e = e0 + t + k * 512;
                const int s = esrc[e];
                const float w = ew[e];
                const int bq = d[k] >> 5;
                const int pos = atomicAdd(&lcur[bq], 1);
                if (pos < CAPB) {
                    bkt2[(size_t)bq * CAPB + pos] =
                        make_uint2((unsigned)s | bf16hi(w), (unsigned)d[k]);
                } else {
                    const int op = atomicAdd(ovfc, 1);
                    if (op < OVF_CAP) ovf[op] = make_int4(d[k], s, __float_as_int(w), 0);
                }
            }
        }
    }
}

// ---------------- aggregate: block per 32-node bucket, LDS counting sort --
// 256 thr / 4 waves / ~9.6 KB LDS -> 8 blocks/CU; 1563 blocks -> fine-grain
// tail. Stage ~512 records coalesced, LDS-sort by local node, then
// wave-per-node x8: records via LDS broadcast, bf16 row gathers 8-deep,
// f32 register accumulate, plain float2 store.
__global__ __launch_bounds__(256) void srgnn_agg_s32(
    const unsigned* __restrict__ hidU, const int* __restrict__ gcur,
    const uint2* __restrict__ bkt2, const int* __restrict__ ovfc,
    const int4* __restrict__ ovf, float* __restrict__ out)
{
    __shared__ uint2    recs[CAPB];     // 6144 B
    __shared__ unsigned srt[CAPB];      // 3072 B
    __shared__ int nh[32], sc[32], cur[32];

    const int t = threadIdx.x;
    const int bq = blockIdx.x;
    int cntb = gcur[bq];
    if (cntb > CAPB) cntb = CAPB;

    if (t < 32) nh[t] = 0;
    __syncthreads();
    for (int i = t; i < cntb; i += 256) {
        const uint2 r = bkt2[(size_t)bq * CAPB + i];
        recs[i] = r;
        atomicAdd(&nh[r.y & 31], 1);
    }
    __syncthreads();
    if (t < 32) sc[t] = nh[t];
    __syncthreads();
    for (int ofs = 1; ofs < 32; ofs <<= 1) {         // Hillis-Steele inclusive
        int a = 0;
        if (t < 32 && t >= ofs) a = sc[t - ofs];
        __syncthreads();
        if (t < 32) sc[t] += a;
        __syncthreads();
    }
    if (t < 32) cur[t] = sc[t] - nh[t];
    __syncthreads();
    for (int i = t; i < cntb; i += 256) {
        const uint2 r = recs[i];
        const int pos = atomicAdd(&cur[r.y & 31], 1);
        srt[pos] = r.x;                              // src | bf16(w)<<16
    }
    __syncthreads();

    int oc = *ovfc;                                  // ~always 0
    if (oc > OVF_CAP) oc = OVF_CAP;
    const int lane = t & 63;
    const int wid  = t >> 6;                         // 4 waves
    const bool active = (lane < 50);

    for (int q = 0; q < 8; ++q) {
        const int n  = wid * 8 + q;                  // 4 waves x 8 = 32 nodes
        const int s1 = sc[n];
        const int s0 = s1 - nh[n];
        float2 acc = make_float2(0.f, 0.f);

        int p = s0;
        for (; p + 8 <= s1; p += 8) {                // 8-deep MLP
            unsigned r[8], h[8];
            #pragma unroll
            for (int j = 0; j < 8; ++j) r[j] = srt[p + j];
            if (active) {
                #pragma unroll
                for (int j = 0; j < 8; ++j)
                    h[j] = hidU[(size_t)(r[j] & 0xFFFFu) * 50 + lane];
                #pragma unroll
                for (int j = 0; j < 8; ++j) {
                    const float wj = __uint_as_float(r[j] & 0xFFFF0000u);
                    acc.x += wj * __uint_as_float(h[j] << 16);
                    acc.y += wj * __uint_as_float(h[j] & 0xFFFF0000u);
                }
            }
        }
        for (; p < s1; ++p) {
            const unsigned r = srt[p];
            const float wi = __uint_as_float(r & 0xFFFF0000u);
            if (active) {
                const unsigned h = hidU[(size_t)(r & 0xFFFFu) * 50 + lane];
                acc.x += wi * __uint_as_float(h << 16);
                acc.y += wi * __uint_as_float(h & 0xFFFF0000u);
            }
        }

        const int ng = bq * 32 + n;
        if (oc > 0) {                                // ultra-rare overflow scan
            for (int i = 0; i < oc; ++i) {
                const int4 v = ovf[i];
                if (v.x == ng && active) {
                    const unsigned h = hidU[(size_t)v.y * 50 + lane];
                    const float wi = __int_as_float(v.z);
                    acc.x += wi * __uint_as_float(h << 16);
                    acc.y += wi * __uint_as_float(h & 0xFFFF0000u);
                }
            }
        }
        if (ng < N_NODES && active)
            *reinterpret_cast<float2*>(&out[(size_t)ng * DIM + 2 * lane]) = acc;
    }
}

// ---------------- fallback (atomic scatter, needs only 20MB ws) ----------
__global__ __launch_bounds__(256) void srgnn_gemm_bias(
    const float* __restrict__ x, const float* __restrict__ W,
    const float* __restrict__ b, float* __restrict__ hidden)
{
    __shared__ float Wt[DIM][DIM + 4];
    __shared__ float bs[DIM];
    __shared__ float xs[8][DIM];
    const int t = threadIdx.x;
    for (int i = t; i < DIM * DIM; i += 256) {
        int c = i / DIM, k = i - c * DIM;
        Wt[k][c] = W[i];
    }
    if (t < DIM) bs[t] = b[t];
    const int row0 = blockIdx.x * 8;
    for (int i = t; i < 8 * DIM; i += 256) {
        int r = i / DIM, k = i - r * DIM;
        int row = row0 + r;
        xs[r][k] = (row < N_NODES) ? x[row * DIM + k] : 0.0f;
    }
    __syncthreads();
    if (t < 200) {
        const int r  = t / 25;
        const int c4 = (t - r * 25) * 4;
        float acc0 = bs[c4 + 0], acc1 = bs[c4 + 1], acc2 = bs[c4 + 2], acc3 = bs[c4 + 3];
        for (int k = 0; k < DIM; ++k) {
            const float xv = xs[r][k];
            const float4 wv = *reinterpret_cast<const float4*>(&Wt[k][c4]);
            acc0 += xv * wv.x; acc1 += xv * wv.y; acc2 += xv * wv.z; acc3 += xv * wv.w;
        }
        const int row = row0 + r;
        if (row < N_NODES)
            *reinterpret_cast<float4*>(&hidden[row * DIM + c4]) =
                make_float4(acc0, acc1, acc2, acc3);
    }
}

__global__ __launch_bounds__(256) void srgnn_scatter_atomic(
    const float* __restrict__ hidden, const int* __restrict__ esrc,
    const int* __restrict__ edst, const float* __restrict__ ew,
    float* __restrict__ out)
{
    const unsigned gid = blockIdx.x * 256u + threadIdx.x;
    const unsigned e = gid / 25u;
    const unsigned j = gid - e * 25u;
    if (e >= N_EDGES) return;
    const int   s  = esrc[e];
    const int   d  = edst[e];
    const float wt = ew[e];
    const float4 h = *reinterpret_cast<const float4*>(&hidden[(size_t)s * DIM + j * 4]);
    float* op = &out[(size_t)d * DIM + j * 4];
    atomicAdd(op + 0, h.x * wt);
    atomicAdd(op + 1, h.y * wt);
    atomicAdd(op + 2, h.z * wt);
    atomicAdd(op + 3, h.w * wt);
}

extern "C" void kernel_launch(void* const* d_in, const int* in_sizes, int n_in,
                              void* d_out, int out_size, void* d_ws, size_t ws_size,
                              hipStream_t stream) {
    const float* x    = (const float*)d_in[0];
    const int*   esrc = (const int*)  d_in[1];
    const int*   edst = (const int*)  d_in[2];
    const float* ew   = (const float*)d_in[3];
    const float* W    = (const float*)d_in[4];
    const float* b    = (const float*)d_in[5];
    float* out = (float*)d_out;

    char* ws = (char*)d_ws;

    if (ws_size >= WS_NEED) {
        unsigned* hidU = (unsigned*)(ws + HIDB_OFF);
        int*      gcur = (int*)     (ws + GCUR_OFF);
        int*      ovfc = (int*)     (ws + OVFC_OFF);
        int4*     ovf  = (int4*)    (ws + OVF_OFF);
        uint2*    bkt2 = (uint2*)   (ws + BKT2_OFF);
        float*    Wt   = (float*)   (ws + WT_OFF);

        // transpose W + zero control buffers (one dispatch)
        srgnn_transpose<<<(DIM * DIM + 255) / 256, 256, 0, stream>>>(W, Wt, gcur, ovfc);
        // fused: GEMM (625 blocks) + edge binning (98 blocks), co-resident
        srgnn_gemm_bin<<<GEMM_BLOCKS + BIN_BLOCKS, 512, 0, stream>>>(
            x, Wt, b, hidU, esrc, edst, ew, gcur, ovfc, ovf, bkt2);
        // block-per-bucket LDS sort + aggregate
        srgnn_agg_s32<<<NB, 256, 0, stream>>>(hidU, gcur, bkt2, ovfc, ovf, out);
    } else {
        // fallback: atomic scatter
        float* hidden = (float*)ws;
        hipMemsetAsync(d_out, 0, (size_t)out_size * sizeof(float), stream);
        const int gemm_blocks = (N_NODES + 7) / 8;
        srgnn_gemm_bias<<<gemm_blocks, 256, 0, stream>>>(x, W, b, hidden);
        const long long work = (long long)N_EDGES * 25;
        const int scat_blocks = (int)((work + 255) / 256);
        srgnn_scatter_atomic<<<scat_blocks, 256, 0, stream>>>(hidden, esrc, edst, ew, out);
    }
}